// Round 1
// 415.066 us; speedup vs baseline: 1.0070x; 1.0070x over previous
//
#include <hip/hip_runtime.h>
#include <math.h>

#define D 128
#define NB 4      // num bases
#define NR 8      // num relations
#define NLAYER 2
#define KTOT 640  // 512 (bases) + 128 (root)
#define EPSV 1e-5f
#define SLOPE 0.2f
#define NBUK 32
#define BSHIFT 11   // bucket = dst >> 11

typedef __attribute__((ext_vector_type(8))) short short8;   // 8 bf16 = 4 VGPRs
typedef __attribute__((ext_vector_type(4))) float f32x4;

__device__ __forceinline__ unsigned short f2bf(float f) {
  unsigned u = __float_as_uint(f);
  u += 0x7FFF + ((u >> 16) & 1);          // round-to-nearest-even
  return (unsigned short)(u >> 16);
}

// ---------------- block reduction (128 threads = 2 waves) ----------------
__device__ __forceinline__ float block_sum_128(float v, volatile float* scratch) {
#pragma unroll
  for (int off = 32; off > 0; off >>= 1) v += __shfl_xor(v, off);
  __syncthreads();
  if ((threadIdx.x & 63) == 0) scratch[threadIdx.x >> 6] = v;
  __syncthreads();
  return scratch[0] + scratch[1];
}

// ---------------- CSR build ----------------
__global__ void hist_kernel(const int* __restrict__ dst, int* __restrict__ deg, int E) {
  int e = blockIdx.x * 256 + threadIdx.x;
  if (e < E) atomicAdd(&deg[dst[e]], 1);
}

// single-block scan of deg -> offs/cur; also inits padded bucket cursors bcur[b*16]=offs[b<<BSHIFT]
__global__ void __launch_bounds__(1024) scan_kernel(const int* __restrict__ deg,
                                                    int* __restrict__ offs,
                                                    int* __restrict__ cur,
                                                    int* __restrict__ bcur, int n) {
  __shared__ int wsums[16];
  const int tid = threadIdx.x, lane = tid & 63, wid = tid >> 6;
  int carry = 0;
  for (int base = 0; base < n; base += 4096) {
    int i0 = base + tid * 4;
    int v0 = 0, v1 = 0, v2 = 0, v3 = 0;
    if (i0 + 3 < n) {
      int4 q = *(const int4*)(deg + i0);
      v0 = q.x; v1 = q.y; v2 = q.z; v3 = q.w;
    } else if (i0 < n) {
      v0 = deg[i0];
      if (i0 + 1 < n) v1 = deg[i0 + 1];
      if (i0 + 2 < n) v2 = deg[i0 + 2];
    }
    int tsum = v0 + v1 + v2 + v3;
    int x = tsum;
#pragma unroll
    for (int off = 1; off < 64; off <<= 1) {
      int y = __shfl_up(x, off);
      if (lane >= off) x += y;
    }
    if (lane == 63) wsums[wid] = x;
    __syncthreads();
    if (wid == 0) {
      int ws = (lane < 16) ? wsums[lane] : 0;
#pragma unroll
      for (int off = 1; off < 16; off <<= 1) {
        int y = __shfl_up(ws, off);
        if (lane >= off) ws += y;
      }
      if (lane < 16) wsums[lane] = ws;
    }
    __syncthreads();
    int prefix = carry + ((wid > 0) ? wsums[wid - 1] : 0) + x - tsum;
    int e0 = prefix, e1 = e0 + v0, e2 = e1 + v1, e3 = e2 + v2;
    if (i0 < n)     { offs[i0] = e0;     cur[i0] = e0; }
    if (i0 + 1 < n) { offs[i0 + 1] = e1; cur[i0 + 1] = e1; }
    if (i0 + 2 < n) { offs[i0 + 2] = e2; cur[i0 + 2] = e2; }
    if (i0 + 3 < n) { offs[i0 + 3] = e3; cur[i0 + 3] = e3; }
    int btot = wsums[15];
    __syncthreads();
    carry += btot;
  }
  if (tid == 0) offs[n] = carry;
  __syncthreads();                       // offs[] visible within this (single) workgroup
  if (tid < NBUK) {
    int idx = tid << BSHIFT;
    bcur[tid * 16] = offs[idx < n ? idx : n];
  }
}

// Pass B: bucket edges by dst>>BSHIFT into ebuf (8B records, ~contiguous runs per bucket)
__global__ void __launch_bounds__(1024) bucket_kernel(
    const int* __restrict__ src, const int* __restrict__ dst, const int* __restrict__ et,
    int* __restrict__ bcur, unsigned long long* __restrict__ ebuf, int E) {
  __shared__ int lcnt[NBUK];
  __shared__ int lbase[NBUK];
  const int tid = threadIdx.x;
  const int e = blockIdx.x * 1024 + tid;
  if (tid < NBUK) lcnt[tid] = 0;
  __syncthreads();
  int d = 0, b = 0, rank = 0;
  unsigned pk = 0;
  bool valid = e < E;
  if (valid) {
    d = dst[e];
    pk = (unsigned)src[e] | ((unsigned)et[e] << 16);
    b = d >> BSHIFT;
    rank = atomicAdd(&lcnt[b], 1);
  }
  __syncthreads();
  if (tid < NBUK && lcnt[tid] > 0) lbase[tid] = atomicAdd(&bcur[tid * 16], lcnt[tid]);
  __syncthreads();
  if (valid) ebuf[lbase[b] + rank] = ((unsigned long long)(unsigned)d << 32) | pk;
}

// Pass C: scatter bucket-sorted records into csr (writes confined to ~130KB regions -> L2-merged)
__global__ void scatter2_kernel(const unsigned long long* __restrict__ ebuf,
                                int* __restrict__ cur, unsigned* __restrict__ csr, int E) {
  int e = blockIdx.x * 256 + threadIdx.x;
  if (e < E) {
    unsigned long long r = ebuf[e];
    int d = (int)(r >> 32);
    int pos = atomicAdd(&cur[d], 1);
    csr[pos] = (unsigned)r;
  }
}

// ---------------- fused weight prep (both layers): BT + av ----------------
__global__ void __launch_bounds__(128) prep_w(const float* __restrict__ basis,
                                              const float* __restrict__ root,
                                              const float* __restrict__ att,
                                              unsigned short* __restrict__ BT0,
                                              unsigned short* __restrict__ BT1,
                                              float* __restrict__ av0, float* __restrict__ av1) {
  __shared__ float scratch[2];
  int k = blockIdx.x, l = 0;
  if (k >= KTOT) { k -= KTOT; l = 1; }
  const float* basis_l = basis + (size_t)l * NB * D * D;
  const float* root_l  = root + (size_t)l * D * D;
  const float* att_l   = att + (size_t)l * 2 * D;
  unsigned short* BT = l ? BT1 : BT0;
  float* av = l ? av1 : av0;
  const int o = threadIdx.x;
  float v = (k < 512) ? basis_l[(size_t)(k >> 7) * (D * D) + (size_t)(k & 127) * D + o]
                      : root_l[(size_t)(k - 512) * D + o];
  BT[(size_t)o * KTOT + k] = f2bf(v);
  float w = (k < 512) ? att_l[D + o] : att_l[o];
  float s = block_sum_128(v * w, scratch);
  if (o == 0) av[k] = s;
}

// ---------------- prep_xa: bf16-cast x into ga xb cols + layer-0 ai/ajb (1 wave/node) ------
__global__ void __launch_bounds__(256) prep_xa(const float* __restrict__ x0,
                                               const float* __restrict__ av,
                                               unsigned short* __restrict__ ga,
                                               float* __restrict__ ai,
                                               float* __restrict__ ajb, int N, int Npad) {
  int n = blockIdx.x * 4 + (threadIdx.x >> 6);
  int lane = threadIdx.x & 63;
  if (n >= Npad) return;
  if (n >= N) {                           // zero-pad row (wave-uniform branch)
    *(unsigned*)(ga + (size_t)n * KTOT + 512 + 2 * lane) = 0;
    return;
  }
  float2 xv = *(const float2*)(x0 + (size_t)n * D + 2 * lane);
  unsigned packed = (unsigned)f2bf(xv.x) | ((unsigned)f2bf(xv.y) << 16);
  *(unsigned*)(ga + (size_t)n * KTOT + 512 + 2 * lane) = packed;
  float d[5];
#pragma unroll
  for (int b = 0; b < 4; ++b) {
    float2 w = *(const float2*)(av + b * D + 2 * lane);
    d[b] = xv.x * w.x + xv.y * w.y;
  }
  {
    float2 w = *(const float2*)(av + 512 + 2 * lane);
    d[4] = xv.x * w.x + xv.y * w.y;
  }
#pragma unroll
  for (int off = 1; off < 64; off <<= 1) {
#pragma unroll
    for (int i = 0; i < 5; ++i) d[i] += __shfl_xor(d[i], off);
  }
  if (lane == 0) {
    *(float4*)(ajb + (size_t)n * 4) = make_float4(d[0], d[1], d[2], d[3]);
    ai[n] = d[4];
  }
}

// ---------------- per-node attention scalars (layer 1): one wave per node ----------------
__global__ void __launch_bounds__(256) a2_kernel(const unsigned short* __restrict__ ga,
                                                 const float* __restrict__ av,
                                                 float* __restrict__ ai,
                                                 float* __restrict__ ajb, int N) {
  int n = blockIdx.x * 4 + (threadIdx.x >> 6);
  int lane = threadIdx.x & 63;
  if (n >= N) return;
  unsigned xv = *(const unsigned*)(ga + (size_t)n * KTOT + 512 + 2 * lane);
  float x0 = __uint_as_float(xv << 16);
  float x1 = __uint_as_float(xv & 0xFFFF0000u);
  float d[5];
#pragma unroll
  for (int b = 0; b < 4; ++b) {
    float2 w = *(const float2*)(av + b * D + 2 * lane);
    d[b] = x0 * w.x + x1 * w.y;
  }
  {
    float2 w = *(const float2*)(av + 512 + 2 * lane);
    d[4] = x0 * w.x + x1 * w.y;
  }
#pragma unroll
  for (int off = 1; off < 64; off <<= 1) {
#pragma unroll
    for (int i = 0; i < 5; ++i) d[i] += __shfl_xor(d[i], off);
  }
  if (lane == 0) {
    *(float4*)(ajb + (size_t)n * 4) = make_float4(d[0], d[1], d[2], d[3]);
    ai[n] = d[4];
  }
}

// ---------------- softmax + x-space scatter: 4 NODES/WAVE, 16 lanes/node ----------
// No max-subtraction: |alpha| <= ||x||*||att|| < ~8 deterministically (layer0 x ~ N(0,1),
// layer1 x in (-1,1)), so exp(alpha) < ~3e3 -> fp32-safe; softmax result identical.
// Each lane covers 8 dims (dwordx4 gather); 4 rows in flight per load instr (4x MLP).
__global__ void __launch_bounds__(256) node_flash(
    unsigned short* __restrict__ ga, const float* __restrict__ ai, const float* __restrict__ ajb,
    const int* __restrict__ offs, const unsigned* __restrict__ csr,
    const float* __restrict__ attr_l, int N) {
  __shared__ float s_c[NR * NB];
  __shared__ float4 s_wc[4][64];          // per-wave; group g owns slots [g*16, g*16+16)
  __shared__ unsigned s_pk[4][64];
  const int w = threadIdx.x >> 6, lane = threadIdx.x & 63;
  const int g = lane >> 4, s = lane & 15;
  const int n = blockIdx.x * 16 + w * 4 + g;
  if (lane < NR * NB) s_c[lane] = attr_l[lane];  // all waves write identical values (benign)
  int b0 = 0, b1 = 0;
  float ain = 0.f;
  if (n < N) { b0 = offs[n]; b1 = offs[n + 1]; ain = ai[n]; }
  float ssum = 0.f;
  float acc[4][8];
#pragma unroll
  for (int b = 0; b < 4; ++b)
#pragma unroll
    for (int d = 0; d < 8; ++d) acc[b][d] = 0.f;

  int nch = (b1 - b0 + 15) >> 4;                  // chunks for this group
  nch = max(nch, __shfl_xor(nch, 16));            // wave-uniform max over 4 groups
  nch = max(nch, __shfl_xor(nch, 32));

  for (int ch = 0; ch < nch; ++ch) {
    const int cb = b0 + (ch << 4);
    const int cnt = min(16, b1 - cb);             // may be <=0 for finished groups
    float ex = 0.f;
    float4 wc = make_float4(0.f, 0.f, 0.f, 0.f);
    unsigned pk = 0;
    if (s < cnt) {
      pk = csr[cb + s];
      unsigned sn = pk & 0xFFFFu, rt = pk >> 16;
      float4 aj = *(const float4*)(ajb + (size_t)sn * 4);
      float4 cv = *(const float4*)(&s_c[rt * 4]); // own wave wrote s_c earlier (program order)
      float a = ain + cv.x * aj.x + cv.y * aj.y + cv.z * aj.z + cv.w * aj.w;
      a = fmaxf(a, SLOPE * a);                    // leaky_relu (slope<1)
      ex = __expf(a);
      ssum += ex;                                 // per-lane partial; reduced once at end
      wc = make_float4(ex * cv.x, ex * cv.y, ex * cv.z, ex * cv.w);
    }
    s_pk[w][lane] = pk;                           // pad slots: pk=0 -> row 0 (L2-hot)
    s_wc[w][lane] = wc;                           // pad slots: wc=0 -> contributes nothing
    int cc = max(cnt, 0);
    cc = max(cc, __shfl_xor(cc, 16));             // wave-uniform j bound
    cc = max(cc, __shfl_xor(cc, 32));
    const float4* wrow = &s_wc[w][g * 16];
    const unsigned* prow = &s_pk[w][g * 16];
    // wave-private LDS region: same-wave write->read ordering via lgkmcnt (compiler)
#pragma unroll 2
    for (int j = 0; j < cc; ++j) {
      float4 wcj = wrow[j];                       // broadcast within group (conflict-free)
      unsigned sn = prow[j] & 0xFFFFu;
      const uint4 q = *(const uint4*)(ga + sn * (unsigned)KTOT + 512u + (unsigned)s * 8u);
      float xl, xh;
#define ACC8(K, QQ)                                           \
      xl = __uint_as_float((QQ) << 16);                       \
      xh = __uint_as_float((QQ) & 0xFFFF0000u);               \
      acc[0][2*K]   = fmaf(wcj.x, xl, acc[0][2*K]);           \
      acc[0][2*K+1] = fmaf(wcj.x, xh, acc[0][2*K+1]);         \
      acc[1][2*K]   = fmaf(wcj.y, xl, acc[1][2*K]);           \
      acc[1][2*K+1] = fmaf(wcj.y, xh, acc[1][2*K+1]);         \
      acc[2][2*K]   = fmaf(wcj.z, xl, acc[2][2*K]);           \
      acc[2][2*K+1] = fmaf(wcj.z, xh, acc[2][2*K+1]);         \
      acc[3][2*K]   = fmaf(wcj.w, xl, acc[3][2*K]);           \
      acc[3][2*K+1] = fmaf(wcj.w, xh, acc[3][2*K+1]);
      ACC8(0, q.x) ACC8(1, q.y) ACC8(2, q.z) ACC8(3, q.w)
#undef ACC8
    }
  }
  // group-wide softmax denominator (offsets <16 stay inside the 16-lane group)
#pragma unroll
  for (int off = 1; off < 16; off <<= 1) ssum += __shfl_xor(ssum, off);
  if (n < N) {
    const float inv = 1.f / (ssum + 1e-16f);
    unsigned short* gp = ga + (size_t)n * KTOT;
#pragma unroll
    for (int b = 0; b < 4; ++b) {
      uint4 r;
      r.x = (unsigned)f2bf(acc[b][0] * inv) | ((unsigned)f2bf(acc[b][1] * inv) << 16);
      r.y = (unsigned)f2bf(acc[b][2] * inv) | ((unsigned)f2bf(acc[b][3] * inv) << 16);
      r.z = (unsigned)f2bf(acc[b][4] * inv) | ((unsigned)f2bf(acc[b][5] * inv) << 16);
      r.w = (unsigned)f2bf(acc[b][6] * inv) | ((unsigned)f2bf(acc[b][7] * inv) << 16);
      *(uint4*)(gp + b * D + s * 8) = r;          // 16 lanes x 16B = contiguous 256B/base
    }
  }
}

// ---------------- MFMA GEMM: out = tanh(LN(ga[N,640]@W[640,128] + bias)) ----------------
// 512 thr = 8 waves, 128 rows/block: 8 waves share each sB stage (half the staging/barriers
// per row vs 4-wave blocks). B staged in 10 k-chunks of 64 (18.4 KB LDS).
// A frag: A[m=l15][k=quad*8+j]; B frag: B[k=quad*8+j][n=l15]; C/D: col=l15, row=quad*4+reg.
__global__ void __launch_bounds__(512) gemm2_kernel(
    unsigned short* __restrict__ ga, const unsigned short* __restrict__ BT,
    const float* __restrict__ bias_l, const float* __restrict__ lnw_l,
    const float* __restrict__ lnb_l, float* __restrict__ st,
    float* __restrict__ xfinal, int n_nodes) {
  __shared__ unsigned short sB[128 * 72];      // [col][k] stride 72 shorts (144 B)
  const int tid = threadIdx.x;
  const int wv = tid >> 6, lane = tid & 63;
  const int l15 = lane & 15, quad = lane >> 4;
  const int rowb = blockIdx.x * 128 + wv * 16;
  const unsigned short* garow = ga + (size_t)(rowb + l15) * KTOT;
  f32x4 acc[8];
  const f32x4 zero = {0.f, 0.f, 0.f, 0.f};
#pragma unroll
  for (int ct = 0; ct < 8; ++ct) acc[ct] = zero;
#pragma unroll
  for (int ch = 0; ch < 10; ++ch) {
    const int k0 = ch * 64;
    short8 a[2];
#pragma unroll
    for (int kc = 0; kc < 2; ++kc)
      a[kc] = *(const short8*)(garow + k0 + kc * 32 + quad * 8);
    __syncthreads();                            // sB consumers of prev chunk done
#pragma unroll
    for (int p = 0; p < 2; ++p) {
      int idx = p * 512 + tid;                  // 1024 = 128 cols x 8 k8
      int col = idx >> 3, k8 = idx & 7;
      *(short8*)(sB + col * 72 + k8 * 8) =
          *(const short8*)(BT + (size_t)col * KTOT + k0 + k8 * 8);
    }
    __syncthreads();
#pragma unroll
    for (int kc = 0; kc < 2; ++kc) {
#pragma unroll
      for (int ct = 0; ct < 8; ++ct) {
        const short8* b = (const short8*)(sB + (ct * 16 + l15) * 72 + kc * 32 + quad * 8);
        acc[ct] = __builtin_amdgcn_mfma_f32_16x16x32_bf16(a[kc], *b, acc[ct], 0, 0, 0);
      }
    }
  }
  // epilogue: + bias, LayerNorm over 128 cols, tanh; write st/xfinal fp32 + next-layer xb bf16
  const int r0 = rowb + quad * 4;
  float bia[8], lw[8], lb[8];
#pragma unroll
  for (int ct = 0; ct < 8; ++ct) {
    int col = ct * 16 + l15;
    bia[ct] = bias_l[col]; lw[ct] = lnw_l[col]; lb[ct] = lnb_l[col];
  }
  float vsum[4] = {0.f, 0.f, 0.f, 0.f}, vsq[4] = {0.f, 0.f, 0.f, 0.f};
#pragma unroll
  for (int ct = 0; ct < 8; ++ct) {
#pragma unroll
    for (int r = 0; r < 4; ++r) {
      float v = acc[ct][r] + bia[ct];
      acc[ct][r] = v;
      vsum[r] += v; vsq[r] += v * v;
    }
  }
#pragma unroll
  for (int r = 0; r < 4; ++r) {
#pragma unroll
    for (int off = 1; off < 16; off <<= 1) {
      vsum[r] += __shfl_xor(vsum[r], off);
      vsq[r]  += __shfl_xor(vsq[r], off);
    }
  }
  float mu[4], rs[4];
#pragma unroll
  for (int r = 0; r < 4; ++r) {
    mu[r] = vsum[r] * (1.0f / D);
    float var = vsq[r] * (1.0f / D) - mu[r] * mu[r];
    rs[r] = rsqrtf(var + EPSV);
  }
#pragma unroll
  for (int ct = 0; ct < 8; ++ct) {
#pragma unroll
    for (int r = 0; r < 4; ++r) {
      int row = r0 + r;
      if (row >= n_nodes) continue;
      int col = ct * 16 + l15;
      float nv = (acc[ct][r] - mu[r]) * rs[r] * lw[ct] + lb[ct];
      float val = tanhf(nv);
      st[(size_t)row * D + col] = val;
      if (xfinal) xfinal[(size_t)row * D + col] = val;
      ga[(size_t)row * KTOT + 512 + col] = f2bf(val);   // next-layer xb (own rows, post-read)
    }
  }
}

// ---------------- launch ----------------
extern "C" void kernel_launch(void* const* d_in, const int* in_sizes, int n_in,
                              void* d_out, int out_size, void* d_ws, size_t ws_size,
                              hipStream_t stream) {
  const float* x0    = (const float*)d_in[0];
  const int*   ei    = (const int*)d_in[1];
  const int*   etype = (const int*)d_in[2];
  const float* basis = (const float*)d_in[3];
  const float* att_r = (const float*)d_in[4];
  const float* att   = (const float*)d_in[5];
  const float* root  = (const float*)d_in[6];
  const float* bias  = (const float*)d_in[7];
  const float* lnw   = (const float*)d_in[8];
  const float* lnb   = (const float*)d_in[9];
  float* out = (float*)d_out;
  const int N = in_sizes[0] / D;
  const int E = in_sizes[2];
  const int Npad = ((N + 127) / 128) * 128;

  char* p = (char*)d_ws;
  auto alloc = [&](size_t bytes) { void* r = (void*)p; p += (bytes + 255) & ~(size_t)255; return r; };
  unsigned short*     ga   = (unsigned short*)alloc((size_t)Npad * KTOT * 2);  // [g(512) | xb(128)]
  unsigned short*     BT0  = (unsigned short*)alloc((size_t)D * KTOT * 2);
  unsigned short*     BT1  = (unsigned short*)alloc((size_t)D * KTOT * 2);
  float*              av0  = (float*)alloc((size_t)KTOT * 4);
  float*              av1  = (float*)alloc((size_t)KTOT * 4);
  float*              ai   = (float*)alloc((size_t)N * 4);
  float*              ajb  = (float*)alloc((size_t)N * 4 * 4);
  int*                deg  = (int*)alloc((size_t)N * 4);
  int*                offs = (int*)alloc((size_t)(N + 1) * 4);
  int*                cur  = (int*)alloc((size_t)N * 4);
  int*                bcur = (int*)alloc((size_t)NBUK * 16 * 4);
  unsigned*           csr  = (unsigned*)alloc((size_t)E * 4);
  unsigned long long* ebuf = (unsigned long long*)alloc((size_t)E * 8);

  const int* srcp = ei;
  const int* dstp = ei + E;

  // CSR by dst: hist -> scan -> bucket (locality) -> scatter
  hipMemsetAsync(deg, 0, (size_t)N * 4, stream);
  hist_kernel<<<(E + 255) / 256, 256, 0, stream>>>(dstp, deg, E);
  scan_kernel<<<1, 1024, 0, stream>>>(deg, offs, cur, bcur, N);
  bucket_kernel<<<(E + 1023) / 1024, 1024, 0, stream>>>(srcp, dstp, etype, bcur, ebuf, E);
  scatter2_kernel<<<(E + 255) / 256, 256, 0, stream>>>(ebuf, cur, csr, E);

  // fused weight prep (both layers) + xb init with layer-0 attention scalars
  prep_w<<<2 * KTOT, 128, 0, stream>>>(basis, root, att, BT0, BT1, av0, av1);
  prep_xa<<<Npad / 4, 256, 0, stream>>>(x0, av0, ga, ai, ajb, N, Npad);

  float* states = out + (size_t)N * D;  // [L, N, D]
  for (int l = 0; l < NLAYER; ++l) {
    const unsigned short* BT_l = l ? BT1 : BT0;
    if (l > 0)  // layer-0 ai/ajb came from prep_xa
      a2_kernel<<<(N + 3) / 4, 256, 0, stream>>>(ga, av1, ai, ajb, N);
    node_flash<<<(N + 15) / 16, 256, 0, stream>>>(ga, ai, ajb, offs, csr,
                                                  att_r + (size_t)l * NR * NB, N);
    float* st = states + (size_t)l * N * D;
    gemm2_kernel<<<Npad / 128, 512, 0, stream>>>(ga, BT_l, bias + (size_t)l * D,
                                                 lnw + (size_t)l * D, lnb + (size_t)l * D,
                                                 st, (l == NLAYER - 1) ? out : nullptr, N);
  }
}

// Round 3
// 392.796 us; speedup vs baseline: 1.0641x; 1.0567x over previous
//
#include <hip/hip_runtime.h>
#include <math.h>

#define D 128
#define NB 4      // num bases
#define NR 8      // num relations
#define NLAYER 2
#define KTOT 640  // 512 (bases) + 128 (root)
#define EPSV 1e-5f
#define SLOPE 0.2f
#define NBUK 32
#define BSHIFT 11   // bucket = dst >> 11

typedef __attribute__((ext_vector_type(8))) short short8;   // 8 bf16 = 4 VGPRs
typedef __attribute__((ext_vector_type(4))) float f32x4;
typedef __attribute__((ext_vector_type(2))) float f32x2;

__device__ __forceinline__ unsigned short f2bf(float f) {
  unsigned u = __float_as_uint(f);
  u += 0x7FFF + ((u >> 16) & 1);          // round-to-nearest-even
  return (unsigned short)(u >> 16);
}

// ---------------- block reduction (128 threads = 2 waves) ----------------
__device__ __forceinline__ float block_sum_128(float v, volatile float* scratch) {
#pragma unroll
  for (int off = 32; off > 0; off >>= 1) v += __shfl_xor(v, off);
  __syncthreads();
  if ((threadIdx.x & 63) == 0) scratch[threadIdx.x >> 6] = v;
  __syncthreads();
  return scratch[0] + scratch[1];
}

// ---------------- CSR build ----------------
__global__ void hist_kernel(const int* __restrict__ dst, int* __restrict__ deg, int E) {
  int e = blockIdx.x * 256 + threadIdx.x;
  if (e < E) atomicAdd(&deg[dst[e]], 1);
}

// single-block scan of deg -> offs/cur; also inits padded bucket cursors bcur[b*16]=offs[b<<BSHIFT]
__global__ void __launch_bounds__(1024) scan_kernel(const int* __restrict__ deg,
                                                    int* __restrict__ offs,
                                                    int* __restrict__ cur,
                                                    int* __restrict__ bcur, int n) {
  __shared__ int wsums[16];
  const int tid = threadIdx.x, lane = tid & 63, wid = tid >> 6;
  int carry = 0;
  for (int base = 0; base < n; base += 4096) {
    int i0 = base + tid * 4;
    int v0 = 0, v1 = 0, v2 = 0, v3 = 0;
    if (i0 + 3 < n) {
      int4 q = *(const int4*)(deg + i0);
      v0 = q.x; v1 = q.y; v2 = q.z; v3 = q.w;
    } else if (i0 < n) {
      v0 = deg[i0];
      if (i0 + 1 < n) v1 = deg[i0 + 1];
      if (i0 + 2 < n) v2 = deg[i0 + 2];
    }
    int tsum = v0 + v1 + v2 + v3;
    int x = tsum;
#pragma unroll
    for (int off = 1; off < 64; off <<= 1) {
      int y = __shfl_up(x, off);
      if (lane >= off) x += y;
    }
    if (lane == 63) wsums[wid] = x;
    __syncthreads();
    if (wid == 0) {
      int ws = (lane < 16) ? wsums[lane] : 0;
#pragma unroll
      for (int off = 1; off < 16; off <<= 1) {
        int y = __shfl_up(ws, off);
        if (lane >= off) ws += y;
      }
      if (lane < 16) wsums[lane] = ws;
    }
    __syncthreads();
    int prefix = carry + ((wid > 0) ? wsums[wid - 1] : 0) + x - tsum;
    int e0 = prefix, e1 = e0 + v0, e2 = e1 + v1, e3 = e2 + v2;
    if (i0 < n)     { offs[i0] = e0;     cur[i0] = e0; }
    if (i0 + 1 < n) { offs[i0 + 1] = e1; cur[i0 + 1] = e1; }
    if (i0 + 2 < n) { offs[i0 + 2] = e2; cur[i0 + 2] = e2; }
    if (i0 + 3 < n) { offs[i0 + 3] = e3; cur[i0 + 3] = e3; }
    int btot = wsums[15];
    __syncthreads();
    carry += btot;
  }
  if (tid == 0) offs[n] = carry;
  __syncthreads();                       // offs[] visible within this (single) workgroup
  if (tid < NBUK) {
    int idx = tid << BSHIFT;
    bcur[tid * 16] = offs[idx < n ? idx : n];
  }
}

// Pass B: bucket edges by dst>>BSHIFT into ebuf (8B records, ~contiguous runs per bucket)
__global__ void __launch_bounds__(1024) bucket_kernel(
    const int* __restrict__ src, const int* __restrict__ dst, const int* __restrict__ et,
    int* __restrict__ bcur, unsigned long long* __restrict__ ebuf, int E) {
  __shared__ int lcnt[NBUK];
  __shared__ int lbase[NBUK];
  const int tid = threadIdx.x;
  const int e = blockIdx.x * 1024 + tid;
  if (tid < NBUK) lcnt[tid] = 0;
  __syncthreads();
  int d = 0, b = 0, rank = 0;
  unsigned pk = 0;
  bool valid = e < E;
  if (valid) {
    d = dst[e];
    pk = (unsigned)src[e] | ((unsigned)et[e] << 16);
    b = d >> BSHIFT;
    rank = atomicAdd(&lcnt[b], 1);
  }
  __syncthreads();
  if (tid < NBUK && lcnt[tid] > 0) lbase[tid] = atomicAdd(&bcur[tid * 16], lcnt[tid]);
  __syncthreads();
  if (valid) ebuf[lbase[b] + rank] = ((unsigned long long)(unsigned)d << 32) | pk;
}

// Pass C: scatter bucket-sorted records into csr (writes confined to ~130KB regions -> L2-merged)
__global__ void scatter2_kernel(const unsigned long long* __restrict__ ebuf,
                                int* __restrict__ cur, unsigned* __restrict__ csr, int E) {
  int e = blockIdx.x * 256 + threadIdx.x;
  if (e < E) {
    unsigned long long r = ebuf[e];
    int d = (int)(r >> 32);
    int pos = atomicAdd(&cur[d], 1);
    csr[pos] = (unsigned)r;
  }
}

// ---------------- fused weight prep (both layers): BT + av ----------------
__global__ void __launch_bounds__(128) prep_w(const float* __restrict__ basis,
                                              const float* __restrict__ root,
                                              const float* __restrict__ att,
                                              unsigned short* __restrict__ BT0,
                                              unsigned short* __restrict__ BT1,
                                              float* __restrict__ av0, float* __restrict__ av1) {
  __shared__ float scratch[2];
  int k = blockIdx.x, l = 0;
  if (k >= KTOT) { k -= KTOT; l = 1; }
  const float* basis_l = basis + (size_t)l * NB * D * D;
  const float* root_l  = root + (size_t)l * D * D;
  const float* att_l   = att + (size_t)l * 2 * D;
  unsigned short* BT = l ? BT1 : BT0;
  float* av = l ? av1 : av0;
  const int o = threadIdx.x;
  float v = (k < 512) ? basis_l[(size_t)(k >> 7) * (D * D) + (size_t)(k & 127) * D + o]
                      : root_l[(size_t)(k - 512) * D + o];
  BT[(size_t)o * KTOT + k] = f2bf(v);
  float w = (k < 512) ? att_l[D + o] : att_l[o];
  float s = block_sum_128(v * w, scratch);
  if (o == 0) av[k] = s;
}

// ---------------- prep_xa: bf16-cast x into ga xb cols + layer-0 ai/ajb (1 wave/node) ------
__global__ void __launch_bounds__(256) prep_xa(const float* __restrict__ x0,
                                               const float* __restrict__ av,
                                               unsigned short* __restrict__ ga,
                                               float* __restrict__ ai,
                                               float* __restrict__ ajb, int N, int Npad) {
  int n = blockIdx.x * 4 + (threadIdx.x >> 6);
  int lane = threadIdx.x & 63;
  if (n >= Npad) return;
  if (n >= N) {                           // zero-pad row (wave-uniform branch)
    *(unsigned*)(ga + (size_t)n * KTOT + 512 + 2 * lane) = 0;
    return;
  }
  float2 xv = *(const float2*)(x0 + (size_t)n * D + 2 * lane);
  unsigned packed = (unsigned)f2bf(xv.x) | ((unsigned)f2bf(xv.y) << 16);
  *(unsigned*)(ga + (size_t)n * KTOT + 512 + 2 * lane) = packed;
  float d[5];
#pragma unroll
  for (int b = 0; b < 4; ++b) {
    float2 w = *(const float2*)(av + b * D + 2 * lane);
    d[b] = xv.x * w.x + xv.y * w.y;
  }
  {
    float2 w = *(const float2*)(av + 512 + 2 * lane);
    d[4] = xv.x * w.x + xv.y * w.y;
  }
#pragma unroll
  for (int off = 1; off < 64; off <<= 1) {
#pragma unroll
    for (int i = 0; i < 5; ++i) d[i] += __shfl_xor(d[i], off);
  }
  if (lane == 0) {
    *(float4*)(ajb + (size_t)n * 4) = make_float4(d[0], d[1], d[2], d[3]);
    ai[n] = d[4];
  }
}

// ---------------- softmax + x-space scatter: 4 NODES/WAVE, 16 lanes/node ----------
// No max-subtraction: |alpha| <= ||x||*||att|| < ~8 deterministically -> exp fp32-safe.
// LDS group stride 17 -> the 4 groups' broadcast ds_read_b128 hit disjoint bank quads.
// Inner loop: v_pk_fma_f32 (f32x2) + unroll 4 -> 4 row-gathers in flight per wave.
__global__ void __launch_bounds__(256) node_flash(
    unsigned short* __restrict__ ga, const float* __restrict__ ai, const float* __restrict__ ajb,
    const int* __restrict__ offs, const unsigned* __restrict__ csr,
    const float* __restrict__ attr_l, int N) {
  __shared__ float s_c[NR * NB];
  __shared__ float4 s_wc[4][68];          // group g owns [g*17, g*17+16)
  __shared__ unsigned s_pk[4][68];
  const int w = threadIdx.x >> 6, lane = threadIdx.x & 63;
  const int g = lane >> 4, s = lane & 15;
  const int gb = g * 17;
  const int n = blockIdx.x * 16 + w * 4 + g;
  if (lane < NR * NB) s_c[lane] = attr_l[lane];  // all waves write identical values (benign)
  int b0 = 0, b1 = 0;
  float ain = 0.f;
  if (n < N) { b0 = offs[n]; b1 = offs[n + 1]; ain = ai[n]; }
  float ssum = 0.f;
  f32x2 acc[4][4];                        // [base][dim-pair]
#pragma unroll
  for (int b = 0; b < 4; ++b)
#pragma unroll
    for (int k = 0; k < 4; ++k) acc[b][k] = (f32x2){0.f, 0.f};

  int nch = (b1 - b0 + 15) >> 4;
  nch = max(nch, __shfl_xor(nch, 16));            // wave-uniform max over 4 groups
  nch = max(nch, __shfl_xor(nch, 32));

  const unsigned short* gax = ga + 512u + (unsigned)s * 8u;

  for (int ch = 0; ch < nch; ++ch) {
    const int cb = b0 + (ch << 4);
    const int cnt = min(16, b1 - cb);             // may be <=0 for finished groups
    float4 wc = make_float4(0.f, 0.f, 0.f, 0.f);
    unsigned pk = 0;
    if (s < cnt) {
      pk = csr[cb + s];
      unsigned sn = pk & 0xFFFFu, rt = pk >> 16;
      float4 aj = *(const float4*)(ajb + (size_t)sn * 4);
      float4 cv = *(const float4*)(&s_c[rt * 4]); // own wave wrote s_c earlier (program order)
      float a = ain + cv.x * aj.x + cv.y * aj.y + cv.z * aj.z + cv.w * aj.w;
      a = fmaxf(a, SLOPE * a);                    // leaky_relu (slope<1)
      float ex = __expf(a);
      ssum += ex;                                 // per-lane partial; reduced once at end
      wc = make_float4(ex * cv.x, ex * cv.y, ex * cv.z, ex * cv.w);
    }
    s_pk[w][gb + s] = pk;                         // pad slots: pk=0 -> row 0 (L2-hot)
    s_wc[w][gb + s] = wc;                         // pad slots: wc=0 -> contributes nothing
    int cc = max(cnt, 0);
    cc = max(cc, __shfl_xor(cc, 16));             // wave-uniform j bound
    cc = max(cc, __shfl_xor(cc, 32));
    const float4* wrow = &s_wc[w][gb];
    const unsigned* prow = &s_pk[w][gb];
    // wave-private LDS region: same-wave write->read ordering via lgkmcnt (compiler)
#pragma unroll 4
    for (int j = 0; j < cc; ++j) {
      float4 wcj = wrow[j];                       // 4 groups -> 4 distinct bank quads
      unsigned sn = prow[j] & 0xFFFFu;
      const uint4 q = *(const uint4*)(gax + sn * (unsigned)KTOT);
      f32x2 W0 = {wcj.x, wcj.x}, W1 = {wcj.y, wcj.y};
      f32x2 W2 = {wcj.z, wcj.z}, W3 = {wcj.w, wcj.w};
#define ACC2(K, QQ) { \
      f32x2 X = { __uint_as_float((QQ) << 16), __uint_as_float((QQ) & 0xFFFF0000u) }; \
      acc[0][K] = __builtin_elementwise_fma(W0, X, acc[0][K]); \
      acc[1][K] = __builtin_elementwise_fma(W1, X, acc[1][K]); \
      acc[2][K] = __builtin_elementwise_fma(W2, X, acc[2][K]); \
      acc[3][K] = __builtin_elementwise_fma(W3, X, acc[3][K]); }
      ACC2(0, q.x) ACC2(1, q.y) ACC2(2, q.z) ACC2(3, q.w)
#undef ACC2
    }
  }
  // group-wide softmax denominator (offsets <16 stay inside the 16-lane group)
#pragma unroll
  for (int off = 1; off < 16; off <<= 1) ssum += __shfl_xor(ssum, off);
  if (n < N) {
    const float inv = 1.f / (ssum + 1e-16f);
    unsigned short* gp = ga + (size_t)n * KTOT;
#pragma unroll
    for (int b = 0; b < 4; ++b) {
      uint4 r;
      r.x = (unsigned)f2bf(acc[b][0].x * inv) | ((unsigned)f2bf(acc[b][0].y * inv) << 16);
      r.y = (unsigned)f2bf(acc[b][1].x * inv) | ((unsigned)f2bf(acc[b][1].y * inv) << 16);
      r.z = (unsigned)f2bf(acc[b][2].x * inv) | ((unsigned)f2bf(acc[b][2].y * inv) << 16);
      r.w = (unsigned)f2bf(acc[b][3].x * inv) | ((unsigned)f2bf(acc[b][3].y * inv) << 16);
      *(uint4*)(gp + b * D + s * 8) = r;          // 16 lanes x 16B = contiguous 256B/base
    }
  }
}

// ---------------- MFMA GEMM: out = tanh(LN(ga[N,640]@W[640,128] + bias)) ----------------
// 512 thr = 8 waves, 128 rows/block. B staged in 10 k-chunks of 64 (18.4 KB LDS).
// Layer 0 additionally fuses a2: next-layer attention scalars ai/ajb from the val registers.
__global__ void __launch_bounds__(512) gemm2_kernel(
    unsigned short* __restrict__ ga, const unsigned short* __restrict__ BT,
    const float* __restrict__ bias_l, const float* __restrict__ lnw_l,
    const float* __restrict__ lnb_l, float* __restrict__ st,
    float* __restrict__ xfinal, const float* __restrict__ avp,
    float* __restrict__ ai, float* __restrict__ ajb, int n_nodes) {
  __shared__ unsigned short sB[128 * 72];      // [col][k] stride 72 shorts (144 B)
  const int tid = threadIdx.x;
  const int wv = tid >> 6, lane = tid & 63;
  const int l15 = lane & 15, quad = lane >> 4;
  const int rowb = blockIdx.x * 128 + wv * 16;
  const unsigned short* garow = ga + (size_t)(rowb + l15) * KTOT;
  f32x4 acc[8];
  const f32x4 zero = {0.f, 0.f, 0.f, 0.f};
#pragma unroll
  for (int ct = 0; ct < 8; ++ct) acc[ct] = zero;
#pragma unroll
  for (int ch = 0; ch < 10; ++ch) {
    const int k0 = ch * 64;
    short8 a[2];
#pragma unroll
    for (int kc = 0; kc < 2; ++kc)
      a[kc] = *(const short8*)(garow + k0 + kc * 32 + quad * 8);
    __syncthreads();                            // sB consumers of prev chunk done
#pragma unroll
    for (int p = 0; p < 2; ++p) {
      int idx = p * 512 + tid;                  // 1024 = 128 cols x 8 k8
      int col = idx >> 3, k8 = idx & 7;
      *(short8*)(sB + col * 72 + k8 * 8) =
          *(const short8*)(BT + (size_t)col * KTOT + k0 + k8 * 8);
    }
    __syncthreads();
#pragma unroll
    for (int kc = 0; kc < 2; ++kc) {
#pragma unroll
      for (int ct = 0; ct < 8; ++ct) {
        const short8* b = (const short8*)(sB + (ct * 16 + l15) * 72 + kc * 32 + quad * 8);
        acc[ct] = __builtin_amdgcn_mfma_f32_16x16x32_bf16(a[kc], *b, acc[ct], 0, 0, 0);
      }
    }
  }
  // epilogue: + bias, LayerNorm over 128 cols, tanh; write st/xfinal fp32 + next-layer xb bf16
  const int r0 = rowb + quad * 4;
  float bia[8], lw[8], lb[8];
#pragma unroll
  for (int ct = 0; ct < 8; ++ct) {
    int col = ct * 16 + l15;
    bia[ct] = bias_l[col]; lw[ct] = lnw_l[col]; lb[ct] = lnb_l[col];
  }
  float vsum[4] = {0.f, 0.f, 0.f, 0.f}, vsq[4] = {0.f, 0.f, 0.f, 0.f};
#pragma unroll
  for (int ct = 0; ct < 8; ++ct) {
#pragma unroll
    for (int r = 0; r < 4; ++r) {
      float v = acc[ct][r] + bia[ct];
      acc[ct][r] = v;
      vsum[r] += v; vsq[r] += v * v;
    }
  }
#pragma unroll
  for (int r = 0; r < 4; ++r) {
#pragma unroll
    for (int off = 1; off < 16; off <<= 1) {
      vsum[r] += __shfl_xor(vsum[r], off);
      vsq[r]  += __shfl_xor(vsq[r], off);
    }
  }
  float mu[4], rs[4];
#pragma unroll
  for (int r = 0; r < 4; ++r) {
    mu[r] = vsum[r] * (1.0f / D);
    float var = vsq[r] * (1.0f / D) - mu[r] * mu[r];
    rs[r] = rsqrtf(var + EPSV);
  }
  float part[4][5];
#pragma unroll
  for (int r = 0; r < 4; ++r)
#pragma unroll
    for (int b = 0; b < 5; ++b) part[r][b] = 0.f;
#pragma unroll
  for (int ct = 0; ct < 8; ++ct) {
    int col = ct * 16 + l15;
    float a0 = 0.f, a1 = 0.f, a2v = 0.f, a3 = 0.f, a4 = 0.f;
    if (avp) {
      a0 = avp[col]; a1 = avp[D + col]; a2v = avp[2 * D + col];
      a3 = avp[3 * D + col]; a4 = avp[4 * D + col];
    }
#pragma unroll
    for (int r = 0; r < 4; ++r) {
      int row = r0 + r;
      if (row >= n_nodes) continue;
      float nv = (acc[ct][r] - mu[r]) * rs[r] * lw[ct] + lb[ct];
      float val = tanhf(nv);
      st[(size_t)row * D + col] = val;
      if (xfinal) xfinal[(size_t)row * D + col] = val;
      ga[(size_t)row * KTOT + 512 + col] = f2bf(val);   // next-layer xb (own rows, post-read)
      if (avp) {
        part[r][0] = fmaf(val, a0, part[r][0]);
        part[r][1] = fmaf(val, a1, part[r][1]);
        part[r][2] = fmaf(val, a2v, part[r][2]);
        part[r][3] = fmaf(val, a3, part[r][3]);
        part[r][4] = fmaf(val, a4, part[r][4]);
      }
    }
  }
  if (avp) {                                    // fused a2: reduce over the 16 col-lanes
#pragma unroll
    for (int off = 1; off < 16; off <<= 1)
#pragma unroll
      for (int r = 0; r < 4; ++r)
#pragma unroll
        for (int b = 0; b < 5; ++b) part[r][b] += __shfl_xor(part[r][b], off);
    if (l15 == 0) {
#pragma unroll
      for (int r = 0; r < 4; ++r) {
        int row = r0 + r;
        if (row < n_nodes) {
          *(float4*)(ajb + (size_t)row * 4) =
              make_float4(part[r][0], part[r][1], part[r][2], part[r][3]);
          ai[row] = part[r][4];
        }
      }
    }
  }
}

// ---------------- launch ----------------
extern "C" void kernel_launch(void* const* d_in, const int* in_sizes, int n_in,
                              void* d_out, int out_size, void* d_ws, size_t ws_size,
                              hipStream_t stream) {
  const float* x0    = (const float*)d_in[0];
  const int*   ei    = (const int*)d_in[1];
  const int*   etype = (const int*)d_in[2];
  const float* basis = (const float*)d_in[3];
  const float* att_r = (const float*)d_in[4];
  const float* att   = (const float*)d_in[5];
  const float* root  = (const float*)d_in[6];
  const float* bias  = (const float*)d_in[7];
  const float* lnw   = (const float*)d_in[8];
  const float* lnb   = (const float*)d_in[9];
  float* out = (float*)d_out;
  const int N = in_sizes[0] / D;
  const int E = in_sizes[2];
  const int Npad = ((N + 127) / 128) * 128;

  char* p = (char*)d_ws;
  auto alloc = [&](size_t bytes) { void* r = (void*)p; p += (bytes + 255) & ~(size_t)255; return r; };
  unsigned short*     ga   = (unsigned short*)alloc((size_t)Npad * KTOT * 2);  // [g(512) | xb(128)]
  unsigned short*     BT0  = (unsigned short*)alloc((size_t)D * KTOT * 2);
  unsigned short*     BT1  = (unsigned short*)alloc((size_t)D * KTOT * 2);
  float*              av0  = (float*)alloc((size_t)KTOT * 4);
  float*              av1  = (float*)alloc((size_t)KTOT * 4);
  float*              ai   = (float*)alloc((size_t)N * 4);
  float*              ajb  = (float*)alloc((size_t)N * 4 * 4);
  int*                deg  = (int*)alloc((size_t)N * 4);
  int*                offs = (int*)alloc((size_t)(N + 1) * 4);
  int*                cur  = (int*)alloc((size_t)N * 4);
  int*                bcur = (int*)alloc((size_t)NBUK * 16 * 4);
  unsigned*           csr  = (unsigned*)alloc((size_t)E * 4);
  unsigned long long* ebuf = (unsigned long long*)alloc((size_t)E * 8);

  const int* srcp = ei;
  const int* dstp = ei + E;

  // CSR by dst: hist -> scan -> bucket (locality) -> scatter
  hipMemsetAsync(deg, 0, (size_t)N * 4, stream);
  hist_kernel<<<(E + 255) / 256, 256, 0, stream>>>(dstp, deg, E);
  scan_kernel<<<1, 1024, 0, stream>>>(deg, offs, cur, bcur, N);
  bucket_kernel<<<(E + 1023) / 1024, 1024, 0, stream>>>(srcp, dstp, etype, bcur, ebuf, E);
  scatter2_kernel<<<(E + 255) / 256, 256, 0, stream>>>(ebuf, cur, csr, E);

  // fused weight prep (both layers) + xb init with layer-0 attention scalars
  prep_w<<<2 * KTOT, 128, 0, stream>>>(basis, root, att, BT0, BT1, av0, av1);
  prep_xa<<<Npad / 4, 256, 0, stream>>>(x0, av0, ga, ai, ajb, N, Npad);

  float* states = out + (size_t)N * D;  // [L, N, D]
  for (int l = 0; l < NLAYER; ++l) {
    const unsigned short* BT_l = l ? BT1 : BT0;
    node_flash<<<(N + 15) / 16, 256, 0, stream>>>(ga, ai, ajb, offs, csr,
                                                  att_r + (size_t)l * NR * NB, N);
    float* st = states + (size_t)l * N * D;
    gemm2_kernel<<<Npad / 128, 512, 0, stream>>>(ga, BT_l, bias + (size_t)l * D,
                                                 lnw + (size_t)l * D, lnb + (size_t)l * D,
                                                 st, (l == NLAYER - 1) ? out : nullptr,
                                                 (l == 0) ? av1 : nullptr, ai, ajb, N);
  }
}

// Round 4
// 380.277 us; speedup vs baseline: 1.0991x; 1.0329x over previous
//
#include <hip/hip_runtime.h>
#include <math.h>

#define D 128
#define NB 4      // num bases
#define NR 8      // num relations
#define NLAYER 2
#define KTOT 640  // 512 (bases) + 128 (root)
#define EPSV 1e-5f
#define SLOPE 0.2f
#define NBUK 32
#define BSHIFT 11   // bucket = dst >> 11

typedef __attribute__((ext_vector_type(8))) short short8;   // 8 bf16 = 4 VGPRs
typedef __attribute__((ext_vector_type(4))) float f32x4;
typedef __attribute__((ext_vector_type(2))) float f32x2;

__device__ __forceinline__ unsigned short f2bf(float f) {
  unsigned u = __float_as_uint(f);
  u += 0x7FFF + ((u >> 16) & 1);          // round-to-nearest-even
  return (unsigned short)(u >> 16);
}

// ---------------- fused prep_w (blocks 0..319, wave-level) + hist (all blocks) -------------
// prep_w: one k-column per wave; 64 lanes cover o in {lane, lane+64} -> pure shuffle reduce.
__global__ void __launch_bounds__(256) prepw_hist(
    const float* __restrict__ basis, const float* __restrict__ root,
    const float* __restrict__ att,
    unsigned short* __restrict__ BT0, unsigned short* __restrict__ BT1,
    float* __restrict__ av0, float* __restrict__ av1,
    const int* __restrict__ dst, int* __restrict__ deg, int E) {
  const int tid = threadIdx.x, lane = tid & 63, wid = tid >> 6;
  if (blockIdx.x < (2 * KTOT) / 4) {            // 320 blocks x 4 waves = 1280 k-columns
    const int kk = blockIdx.x * 4 + wid;
    const int l = kk >= KTOT ? 1 : 0;
    const int k = kk - l * KTOT;
    const float* basis_l = basis + (size_t)l * NB * D * D;
    const float* root_l  = root + (size_t)l * D * D;
    const float* att_l   = att + (size_t)l * 2 * D;
    unsigned short* BT = l ? BT1 : BT0;
    float* av = l ? av1 : av0;
    const int o = lane;
    float v1, v2, w1, w2;
    if (k < 512) {
      const float* bp = basis_l + (size_t)(k >> 7) * (D * D) + (size_t)(k & 127) * D;
      v1 = bp[o]; v2 = bp[o + 64];
      w1 = att_l[D + o]; w2 = att_l[D + o + 64];
    } else {
      const float* rp = root_l + (size_t)(k - 512) * D;
      v1 = rp[o]; v2 = rp[o + 64];
      w1 = att_l[o]; w2 = att_l[o + 64];
    }
    BT[(size_t)o * KTOT + k] = f2bf(v1);
    BT[(size_t)(o + 64) * KTOT + k] = f2bf(v2);
    float sv = v1 * w1 + v2 * w2;
#pragma unroll
    for (int off = 32; off > 0; off >>= 1) sv += __shfl_xor(sv, off);
    if (lane == 0) av[k] = sv;
  }
  // hist: grid-stride over edges
  const int gtid = blockIdx.x * 256 + tid;
  const int nthr = gridDim.x * 256;
  for (int e = gtid; e < E; e += nthr) atomicAdd(&deg[dst[e]], 1);
}

// ---------------- fused: block 0 = serial scan of deg; blocks >=1 = prep_xa ----------------
// Overlaps the single-block scan (GPU otherwise idle) with the N-node x prep.
__global__ void __launch_bounds__(1024) scan_prepxa(
    const int* __restrict__ deg, int* __restrict__ offs, int* __restrict__ cur,
    int* __restrict__ bcur, int n,
    const float* __restrict__ x0, const float* __restrict__ av,
    unsigned short* __restrict__ ga, float* __restrict__ ai, float* __restrict__ ajb,
    int N, int Npad) {
  __shared__ int wsums[16];
  const int tid = threadIdx.x, lane = tid & 63, wid = tid >> 6;
  if (blockIdx.x == 0) {                        // ---- serial chunked scan ----
    int carry = 0;
    for (int base = 0; base < n; base += 4096) {
      int i0 = base + tid * 4;
      int v0 = 0, v1 = 0, v2 = 0, v3 = 0;
      if (i0 + 3 < n) {
        int4 q = *(const int4*)(deg + i0);
        v0 = q.x; v1 = q.y; v2 = q.z; v3 = q.w;
      } else if (i0 < n) {
        v0 = deg[i0];
        if (i0 + 1 < n) v1 = deg[i0 + 1];
        if (i0 + 2 < n) v2 = deg[i0 + 2];
      }
      int tsum = v0 + v1 + v2 + v3;
      int x = tsum;
#pragma unroll
      for (int off = 1; off < 64; off <<= 1) {
        int y = __shfl_up(x, off);
        if (lane >= off) x += y;
      }
      if (lane == 63) wsums[wid] = x;
      __syncthreads();
      if (wid == 0) {
        int ws = (lane < 16) ? wsums[lane] : 0;
#pragma unroll
        for (int off = 1; off < 16; off <<= 1) {
          int y = __shfl_up(ws, off);
          if (lane >= off) ws += y;
        }
        if (lane < 16) wsums[lane] = ws;
      }
      __syncthreads();
      int prefix = carry + ((wid > 0) ? wsums[wid - 1] : 0) + x - tsum;
      int e0 = prefix, e1 = e0 + v0, e2 = e1 + v1, e3 = e2 + v2;
      if (i0 < n)     { offs[i0] = e0;     cur[i0] = e0; }
      if (i0 + 1 < n) { offs[i0 + 1] = e1; cur[i0 + 1] = e1; }
      if (i0 + 2 < n) { offs[i0 + 2] = e2; cur[i0 + 2] = e2; }
      if (i0 + 3 < n) { offs[i0 + 3] = e3; cur[i0 + 3] = e3; }
      int btot = wsums[15];
      __syncthreads();
      carry += btot;
    }
    if (tid == 0) offs[n] = carry;
    __syncthreads();
    if (tid < NBUK) {
      int idx = tid << BSHIFT;
      bcur[tid * 16] = offs[idx < n ? idx : n];
    }
    return;
  }
  // ---- prep_xa: 16 waves/block, one node per wave ----
  const int nn = (blockIdx.x - 1) * 16 + wid;
  if (nn >= Npad) return;
  if (nn >= N) {                           // zero-pad row (wave-uniform branch)
    *(unsigned*)(ga + (size_t)nn * KTOT + 512 + 2 * lane) = 0;
    return;
  }
  float2 xv = *(const float2*)(x0 + (size_t)nn * D + 2 * lane);
  unsigned packed = (unsigned)f2bf(xv.x) | ((unsigned)f2bf(xv.y) << 16);
  *(unsigned*)(ga + (size_t)nn * KTOT + 512 + 2 * lane) = packed;
  float d[5];
#pragma unroll
  for (int b = 0; b < 4; ++b) {
    float2 w = *(const float2*)(av + b * D + 2 * lane);
    d[b] = xv.x * w.x + xv.y * w.y;
  }
  {
    float2 w = *(const float2*)(av + 512 + 2 * lane);
    d[4] = xv.x * w.x + xv.y * w.y;
  }
#pragma unroll
  for (int off = 1; off < 64; off <<= 1) {
#pragma unroll
    for (int i = 0; i < 5; ++i) d[i] += __shfl_xor(d[i], off);
  }
  if (lane == 0) {
    *(float4*)(ajb + (size_t)nn * 4) = make_float4(d[0], d[1], d[2], d[3]);
    ai[nn] = d[4];
  }
}

// Pass B: bucket edges by dst>>BSHIFT into ebuf (8B records, ~contiguous runs per bucket)
__global__ void __launch_bounds__(1024) bucket_kernel(
    const int* __restrict__ src, const int* __restrict__ dst, const int* __restrict__ et,
    int* __restrict__ bcur, unsigned long long* __restrict__ ebuf, int E) {
  __shared__ int lcnt[NBUK];
  __shared__ int lbase[NBUK];
  const int tid = threadIdx.x;
  const int e = blockIdx.x * 1024 + tid;
  if (tid < NBUK) lcnt[tid] = 0;
  __syncthreads();
  int d = 0, b = 0, rank = 0;
  unsigned pk = 0;
  bool valid = e < E;
  if (valid) {
    d = dst[e];
    pk = (unsigned)src[e] | ((unsigned)et[e] << 16);
    b = d >> BSHIFT;
    rank = atomicAdd(&lcnt[b], 1);
  }
  __syncthreads();
  if (tid < NBUK && lcnt[tid] > 0) lbase[tid] = atomicAdd(&bcur[tid * 16], lcnt[tid]);
  __syncthreads();
  if (valid) ebuf[lbase[b] + rank] = ((unsigned long long)(unsigned)d << 32) | pk;
}

// Pass C: scatter bucket-sorted records into csr (writes confined to ~130KB regions -> L2-merged)
__global__ void scatter2_kernel(const unsigned long long* __restrict__ ebuf,
                                int* __restrict__ cur, unsigned* __restrict__ csr, int E) {
  int e = blockIdx.x * 256 + threadIdx.x;
  if (e < E) {
    unsigned long long r = ebuf[e];
    int d = (int)(r >> 32);
    int pos = atomicAdd(&cur[d], 1);
    csr[pos] = (unsigned)r;
  }
}

// ---------------- softmax + x-space scatter: 4 NODES/WAVE, 16 lanes/node ----------
// No max-subtraction: |alpha| <= ||x||*||att|| < ~8 deterministically -> exp fp32-safe.
// 4 node-tiles per block (grid-stride); LDS group stride 17 (conflict-free broadcast);
// manual 4-wide gather batches: 16 random rows in flight per wave, scheduler-independent.
__global__ void __launch_bounds__(256) node_flash(
    unsigned short* __restrict__ ga, const float* __restrict__ ai, const float* __restrict__ ajb,
    const int* __restrict__ offs, const unsigned* __restrict__ csr,
    const float* __restrict__ attr_l, int N) {
  __shared__ float s_c[NR * NB];
  __shared__ float4 s_wc[4][68];          // group g owns [g*17, g*17+16)
  __shared__ unsigned s_pk[4][68];
  const int w = threadIdx.x >> 6, lane = threadIdx.x & 63;
  const int g = lane >> 4, s = lane & 15;
  const int gb = g * 17;
  if (lane < NR * NB) s_c[lane] = attr_l[lane];  // all waves write identical values (benign)
  const unsigned short* gax = ga + 512u + (unsigned)s * 8u;
  const int base0 = blockIdx.x * 64;

  for (int t = 0; t < 4; ++t) {
    const int n = base0 + t * 16 + w * 4 + g;
    int b0 = 0, b1 = 0;
    float ain = 0.f;
    if (n < N) { b0 = offs[n]; b1 = offs[n + 1]; ain = ai[n]; }
    float ssum = 0.f;
    f32x2 acc[4][4];                        // [base][dim-pair]
#pragma unroll
    for (int b = 0; b < 4; ++b)
#pragma unroll
      for (int k = 0; k < 4; ++k) acc[b][k] = (f32x2){0.f, 0.f};

    int nch = (b1 - b0 + 15) >> 4;
    nch = max(nch, __shfl_xor(nch, 16));          // wave-uniform max over 4 groups
    nch = max(nch, __shfl_xor(nch, 32));

    for (int ch = 0; ch < nch; ++ch) {
      const int cb = b0 + (ch << 4);
      const int cnt = min(16, b1 - cb);           // may be <=0 for finished groups
      float4 wc = make_float4(0.f, 0.f, 0.f, 0.f);
      unsigned pk = 0;
      if (s < cnt) {
        pk = csr[cb + s];
        unsigned sn = pk & 0xFFFFu, rt = pk >> 16;
        float4 aj = *(const float4*)(ajb + (size_t)sn * 4);
        float4 cv = *(const float4*)(&s_c[rt * 4]);
        float a = ain + cv.x * aj.x + cv.y * aj.y + cv.z * aj.z + cv.w * aj.w;
        a = fmaxf(a, SLOPE * a);                  // leaky_relu (slope<1)
        float ex = __expf(a);
        ssum += ex;                               // per-lane partial; reduced once at end
        wc = make_float4(ex * cv.x, ex * cv.y, ex * cv.z, ex * cv.w);
      }
      s_pk[w][gb + s] = pk;                       // ALL 16 slots written every chunk
      s_wc[w][gb + s] = wc;                       // pad slots: wc=0 -> contributes nothing
      int cc = max(cnt, 0);
      cc = max(cc, __shfl_xor(cc, 16));           // wave-uniform j bound
      cc = max(cc, __shfl_xor(cc, 32));
      cc = (cc + 3) & ~3;                         // round to 4: pad slots are zeroed
      const float4* wrow = &s_wc[w][gb];
      const unsigned* prow = &s_pk[w][gb];
      // wave-private LDS region: same-wave write->read ordering via lgkmcnt (compiler)
#define ACCROW(WC, QQ) { \
      f32x2 W0 = {(WC).x, (WC).x}, W1 = {(WC).y, (WC).y}; \
      f32x2 W2 = {(WC).z, (WC).z}, W3 = {(WC).w, (WC).w}; \
      f32x2 X0 = { __uint_as_float((QQ).x << 16), __uint_as_float((QQ).x & 0xFFFF0000u) }; \
      f32x2 X1 = { __uint_as_float((QQ).y << 16), __uint_as_float((QQ).y & 0xFFFF0000u) }; \
      f32x2 X2 = { __uint_as_float((QQ).z << 16), __uint_as_float((QQ).z & 0xFFFF0000u) }; \
      f32x2 X3 = { __uint_as_float((QQ).w << 16), __uint_as_float((QQ).w & 0xFFFF0000u) }; \
      acc[0][0] = __builtin_elementwise_fma(W0, X0, acc[0][0]); \
      acc[0][1] = __builtin_elementwise_fma(W0, X1, acc[0][1]); \
      acc[0][2] = __builtin_elementwise_fma(W0, X2, acc[0][2]); \
      acc[0][3] = __builtin_elementwise_fma(W0, X3, acc[0][3]); \
      acc[1][0] = __builtin_elementwise_fma(W1, X0, acc[1][0]); \
      acc[1][1] = __builtin_elementwise_fma(W1, X1, acc[1][1]); \
      acc[1][2] = __builtin_elementwise_fma(W1, X2, acc[1][2]); \
      acc[1][3] = __builtin_elementwise_fma(W1, X3, acc[1][3]); \
      acc[2][0] = __builtin_elementwise_fma(W2, X0, acc[2][0]); \
      acc[2][1] = __builtin_elementwise_fma(W2, X1, acc[2][1]); \
      acc[2][2] = __builtin_elementwise_fma(W2, X2, acc[2][2]); \
      acc[2][3] = __builtin_elementwise_fma(W2, X3, acc[2][3]); \
      acc[3][0] = __builtin_elementwise_fma(W3, X0, acc[3][0]); \
      acc[3][1] = __builtin_elementwise_fma(W3, X1, acc[3][1]); \
      acc[3][2] = __builtin_elementwise_fma(W3, X2, acc[3][2]); \
      acc[3][3] = __builtin_elementwise_fma(W3, X3, acc[3][3]); }
      for (int jb = 0; jb < cc; jb += 4) {
        float4 wa = wrow[jb + 0], wb = wrow[jb + 1];
        float4 wcv = wrow[jb + 2], wd = wrow[jb + 3];
        unsigned pa = prow[jb + 0], pb = prow[jb + 1];
        unsigned pc = prow[jb + 2], pd = prow[jb + 3];
        const uint4 qa = *(const uint4*)(gax + (pa & 0xFFFFu) * (unsigned)KTOT);
        const uint4 qb = *(const uint4*)(gax + (pb & 0xFFFFu) * (unsigned)KTOT);
        const uint4 qc = *(const uint4*)(gax + (pc & 0xFFFFu) * (unsigned)KTOT);
        const uint4 qd = *(const uint4*)(gax + (pd & 0xFFFFu) * (unsigned)KTOT);
        ACCROW(wa, qa) ACCROW(wb, qb) ACCROW(wcv, qc) ACCROW(wd, qd)
      }
#undef ACCROW
    }
    // group-wide softmax denominator (offsets <16 stay inside the 16-lane group)
#pragma unroll
    for (int off = 1; off < 16; off <<= 1) ssum += __shfl_xor(ssum, off);
    if (n < N) {
      const float inv = 1.f / (ssum + 1e-16f);
      unsigned short* gp = ga + (size_t)n * KTOT;
#pragma unroll
      for (int b = 0; b < 4; ++b) {
        uint4 r;
        r.x = (unsigned)f2bf(acc[b][0].x * inv) | ((unsigned)f2bf(acc[b][0].y * inv) << 16);
        r.y = (unsigned)f2bf(acc[b][1].x * inv) | ((unsigned)f2bf(acc[b][1].y * inv) << 16);
        r.z = (unsigned)f2bf(acc[b][2].x * inv) | ((unsigned)f2bf(acc[b][2].y * inv) << 16);
        r.w = (unsigned)f2bf(acc[b][3].x * inv) | ((unsigned)f2bf(acc[b][3].y * inv) << 16);
        *(uint4*)(gp + b * D + s * 8) = r;        // 16 lanes x 16B = contiguous 256B/base
      }
    }
  }
}

// ---------------- MFMA GEMM: out = tanh(LN(ga[N,640]@W[640,128] + bias)) ----------------
// 512 thr = 8 waves, 128 rows/block. B staged in 10 k-chunks of 64 (18.4 KB LDS).
// Layer 0 additionally fuses a2: next-layer attention scalars ai/ajb from the val registers.
__global__ void __launch_bounds__(512) gemm2_kernel(
    unsigned short* __restrict__ ga, const unsigned short* __restrict__ BT,
    const float* __restrict__ bias_l, const float* __restrict__ lnw_l,
    const float* __restrict__ lnb_l, float* __restrict__ st,
    float* __restrict__ xfinal, const float* __restrict__ avp,
    float* __restrict__ ai, float* __restrict__ ajb, int n_nodes) {
  __shared__ unsigned short sB[128 * 72];      // [col][k] stride 72 shorts (144 B)
  const int tid = threadIdx.x;
  const int wv = tid >> 6, lane = tid & 63;
  const int l15 = lane & 15, quad = lane >> 4;
  const int rowb = blockIdx.x * 128 + wv * 16;
  const unsigned short* garow = ga + (size_t)(rowb + l15) * KTOT;
  f32x4 acc[8];
  const f32x4 zero = {0.f, 0.f, 0.f, 0.f};
#pragma unroll
  for (int ct = 0; ct < 8; ++ct) acc[ct] = zero;
#pragma unroll
  for (int ch = 0; ch < 10; ++ch) {
    const int k0 = ch * 64;
    short8 a[2];
#pragma unroll
    for (int kc = 0; kc < 2; ++kc)
      a[kc] = *(const short8*)(garow + k0 + kc * 32 + quad * 8);
    __syncthreads();                            // sB consumers of prev chunk done
#pragma unroll
    for (int p = 0; p < 2; ++p) {
      int idx = p * 512 + tid;                  // 1024 = 128 cols x 8 k8
      int col = idx >> 3, k8 = idx & 7;
      *(short8*)(sB + col * 72 + k8 * 8) =
          *(const short8*)(BT + (size_t)col * KTOT + k0 + k8 * 8);
    }
    __syncthreads();
#pragma unroll
    for (int kc = 0; kc < 2; ++kc) {
#pragma unroll
      for (int ct = 0; ct < 8; ++ct) {
        const short8* b = (const short8*)(sB + (ct * 16 + l15) * 72 + kc * 32 + quad * 8);
        acc[ct] = __builtin_amdgcn_mfma_f32_16x16x32_bf16(a[kc], *b, acc[ct], 0, 0, 0);
      }
    }
  }
  // epilogue: + bias, LayerNorm over 128 cols, tanh; write st/xfinal fp32 + next-layer xb bf16
  const int r0 = rowb + quad * 4;
  float bia[8], lw[8], lb[8];
#pragma unroll
  for (int ct = 0; ct < 8; ++ct) {
    int col = ct * 16 + l15;
    bia[ct] = bias_l[col]; lw[ct] = lnw_l[col]; lb[ct] = lnb_l[col];
  }
  float vsum[4] = {0.f, 0.f, 0.f, 0.f}, vsq[4] = {0.f, 0.f, 0.f, 0.f};
#pragma unroll
  for (int ct = 0; ct < 8; ++ct) {
#pragma unroll
    for (int r = 0; r < 4; ++r) {
      float v = acc[ct][r] + bia[ct];
      acc[ct][r] = v;
      vsum[r] += v; vsq[r] += v * v;
    }
  }
#pragma unroll
  for (int r = 0; r < 4; ++r) {
#pragma unroll
    for (int off = 1; off < 16; off <<= 1) {
      vsum[r] += __shfl_xor(vsum[r], off);
      vsq[r]  += __shfl_xor(vsq[r], off);
    }
  }
  float mu[4], rs[4];
#pragma unroll
  for (int r = 0; r < 4; ++r) {
    mu[r] = vsum[r] * (1.0f / D);
    float var = vsq[r] * (1.0f / D) - mu[r] * mu[r];
    rs[r] = rsqrtf(var + EPSV);
  }
  float part[4][5];
#pragma unroll
  for (int r = 0; r < 4; ++r)
#pragma unroll
    for (int b = 0; b < 5; ++b) part[r][b] = 0.f;
#pragma unroll
  for (int ct = 0; ct < 8; ++ct) {
    int col = ct * 16 + l15;
    float a0 = 0.f, a1 = 0.f, a2v = 0.f, a3 = 0.f, a4 = 0.f;
    if (avp) {
      a0 = avp[col]; a1 = avp[D + col]; a2v = avp[2 * D + col];
      a3 = avp[3 * D + col]; a4 = avp[4 * D + col];
    }
#pragma unroll
    for (int r = 0; r < 4; ++r) {
      int row = r0 + r;
      if (row >= n_nodes) continue;
      float nv = (acc[ct][r] - mu[r]) * rs[r] * lw[ct] + lb[ct];
      float val = tanhf(nv);
      st[(size_t)row * D + col] = val;
      if (xfinal) xfinal[(size_t)row * D + col] = val;
      ga[(size_t)row * KTOT + 512 + col] = f2bf(val);   // next-layer xb (own rows, post-read)
      if (avp) {
        part[r][0] = fmaf(val, a0, part[r][0]);
        part[r][1] = fmaf(val, a1, part[r][1]);
        part[r][2] = fmaf(val, a2v, part[r][2]);
        part[r][3] = fmaf(val, a3, part[r][3]);
        part[r][4] = fmaf(val, a4, part[r][4]);
      }
    }
  }
  if (avp) {                                    // fused a2: reduce over the 16 col-lanes
#pragma unroll
    for (int off = 1; off < 16; off <<= 1)
#pragma unroll
      for (int r = 0; r < 4; ++r)
#pragma unroll
        for (int b = 0; b < 5; ++b) part[r][b] += __shfl_xor(part[r][b], off);
    if (l15 == 0) {
#pragma unroll
      for (int r = 0; r < 4; ++r) {
        int row = r0 + r;
        if (row < n_nodes) {
          *(float4*)(ajb + (size_t)row * 4) =
              make_float4(part[r][0], part[r][1], part[r][2], part[r][3]);
          ai[row] = part[r][4];
        }
      }
    }
  }
}

// ---------------- launch ----------------
extern "C" void kernel_launch(void* const* d_in, const int* in_sizes, int n_in,
                              void* d_out, int out_size, void* d_ws, size_t ws_size,
                              hipStream_t stream) {
  const float* x0    = (const float*)d_in[0];
  const int*   ei    = (const int*)d_in[1];
  const int*   etype = (const int*)d_in[2];
  const float* basis = (const float*)d_in[3];
  const float* att_r = (const float*)d_in[4];
  const float* att   = (const float*)d_in[5];
  const float* root  = (const float*)d_in[6];
  const float* bias  = (const float*)d_in[7];
  const float* lnw   = (const float*)d_in[8];
  const float* lnb   = (const float*)d_in[9];
  float* out = (float*)d_out;
  const int N = in_sizes[0] / D;
  const int E = in_sizes[2];
  const int Npad = ((N + 127) / 128) * 128;

  char* p = (char*)d_ws;
  auto alloc = [&](size_t bytes) { void* r = (void*)p; p += (bytes + 255) & ~(size_t)255; return r; };
  unsigned short*     ga   = (unsigned short*)alloc((size_t)Npad * KTOT * 2);  // [g(512) | xb(128)]
  unsigned short*     BT0  = (unsigned short*)alloc((size_t)D * KTOT * 2);
  unsigned short*     BT1  = (unsigned short*)alloc((size_t)D * KTOT * 2);
  float*              av0  = (float*)alloc((size_t)KTOT * 4);
  float*              av1  = (float*)alloc((size_t)KTOT * 4);
  float*              ai   = (float*)alloc((size_t)N * 4);
  float*              ajb  = (float*)alloc((size_t)N * 4 * 4);
  int*                deg  = (int*)alloc((size_t)N * 4);
  int*                offs = (int*)alloc((size_t)(N + 1) * 4);
  int*                cur  = (int*)alloc((size_t)N * 4);
  int*                bcur = (int*)alloc((size_t)NBUK * 16 * 4);
  unsigned*           csr  = (unsigned*)alloc((size_t)E * 4);
  unsigned long long* ebuf = (unsigned long long*)alloc((size_t)E * 8);

  const int* srcp = ei;
  const int* dstp = ei + E;

  hipMemsetAsync(deg, 0, (size_t)N * 4, stream);
  // fused prep_w + hist (independent work, one dispatch)
  prepw_hist<<<320 + (E + 255) / 256, 256, 0, stream>>>(basis, root, att, BT0, BT1,
                                                        av0, av1, dstp, deg, E);
  // fused scan (block 0) + prep_xa (other blocks): hides the serial scan
  scan_prepxa<<<1 + Npad / 16, 1024, 0, stream>>>(deg, offs, cur, bcur, N,
                                                  x0, av0, ga, ai, ajb, N, Npad);
  bucket_kernel<<<(E + 1023) / 1024, 1024, 0, stream>>>(srcp, dstp, etype, bcur, ebuf, E);
  scatter2_kernel<<<(E + 255) / 256, 256, 0, stream>>>(ebuf, cur, csr, E);

  float* states = out + (size_t)N * D;  // [L, N, D]
  for (int l = 0; l < NLAYER; ++l) {
    const unsigned short* BT_l = l ? BT1 : BT0;
    node_flash<<<(N + 63) / 64, 256, 0, stream>>>(ga, ai, ajb, offs, csr,
                                                  att_r + (size_t)l * NR * NB, N);
    float* st = states + (size_t)l * N * D;
    gemm2_kernel<<<Npad / 128, 512, 0, stream>>>(ga, BT_l, bias + (size_t)l * D,
                                                 lnw + (size_t)l * D, lnb + (size_t)l * D,
                                                 st, (l == NLAYER - 1) ? out : nullptr,
                                                 (l == 0) ? av1 : nullptr, ai, ajb, N);
  }
}

// Round 5
// 376.820 us; speedup vs baseline: 1.1092x; 1.0092x over previous
//
#include <hip/hip_runtime.h>
#include <math.h>

#define D 128
#define NB 4      // num bases
#define NR 8      // num relations
#define NLAYER 2
#define KTOT 640  // 512 (bases) + 128 (root)
#define EPSV 1e-5f
#define SLOPE 0.2f
#define NBUK 32
#define BSHIFT 11   // bucket = dst >> 11

typedef __attribute__((ext_vector_type(8))) short short8;   // 8 bf16 = 4 VGPRs
typedef __attribute__((ext_vector_type(4))) float f32x4;
typedef __attribute__((ext_vector_type(2))) float f32x2;

__device__ __forceinline__ unsigned short f2bf(float f) {
  unsigned u = __float_as_uint(f);
  u += 0x7FFF + ((u >> 16) & 1);          // round-to-nearest-even
  return (unsigned short)(u >> 16);
}

// ---------------- fused prep_w (blocks 0..319, wave-level) + hist (all blocks) -------------
// prep_w: one k-column per wave; 64 lanes cover o in {lane, lane+64} -> pure shuffle reduce.
__global__ void __launch_bounds__(256) prepw_hist(
    const float* __restrict__ basis, const float* __restrict__ root,
    const float* __restrict__ att,
    unsigned short* __restrict__ BT0, unsigned short* __restrict__ BT1,
    float* __restrict__ av0, float* __restrict__ av1,
    const int* __restrict__ dst, int* __restrict__ deg, int E) {
  const int tid = threadIdx.x, lane = tid & 63, wid = tid >> 6;
  if (blockIdx.x < (2 * KTOT) / 4) {            // 320 blocks x 4 waves = 1280 k-columns
    const int kk = blockIdx.x * 4 + wid;
    const int l = kk >= KTOT ? 1 : 0;
    const int k = kk - l * KTOT;
    const float* basis_l = basis + (size_t)l * NB * D * D;
    const float* root_l  = root + (size_t)l * D * D;
    const float* att_l   = att + (size_t)l * 2 * D;
    unsigned short* BT = l ? BT1 : BT0;
    float* av = l ? av1 : av0;
    const int o = lane;
    float v1, v2, w1, w2;
    if (k < 512) {
      const float* bp = basis_l + (size_t)(k >> 7) * (D * D) + (size_t)(k & 127) * D;
      v1 = bp[o]; v2 = bp[o + 64];
      w1 = att_l[D + o]; w2 = att_l[D + o + 64];
    } else {
      const float* rp = root_l + (size_t)(k - 512) * D;
      v1 = rp[o]; v2 = rp[o + 64];
      w1 = att_l[o]; w2 = att_l[o + 64];
    }
    BT[(size_t)o * KTOT + k] = f2bf(v1);
    BT[(size_t)(o + 64) * KTOT + k] = f2bf(v2);
    float sv = v1 * w1 + v2 * w2;
#pragma unroll
    for (int off = 32; off > 0; off >>= 1) sv += __shfl_xor(sv, off);
    if (lane == 0) av[k] = sv;
  }
  // hist: grid-stride over edges
  const int gtid = blockIdx.x * 256 + tid;
  const int nthr = gridDim.x * 256;
  for (int e = gtid; e < E; e += nthr) atomicAdd(&deg[dst[e]], 1);
}

// ---------------- fused: block 0 = serial scan of deg; blocks >=1 = prep_xa ----------------
// Overlaps the single-block scan (GPU otherwise idle) with the N-node x prep.
__global__ void __launch_bounds__(1024) scan_prepxa(
    const int* __restrict__ deg, int* __restrict__ offs, int* __restrict__ cur,
    int* __restrict__ bcur, int n,
    const float* __restrict__ x0, const float* __restrict__ av,
    unsigned short* __restrict__ ga, float* __restrict__ ai, float* __restrict__ ajb,
    int N, int Npad) {
  __shared__ int wsums[16];
  const int tid = threadIdx.x, lane = tid & 63, wid = tid >> 6;
  if (blockIdx.x == 0) {                        // ---- serial chunked scan ----
    int carry = 0;
    for (int base = 0; base < n; base += 4096) {
      int i0 = base + tid * 4;
      int v0 = 0, v1 = 0, v2 = 0, v3 = 0;
      if (i0 + 3 < n) {
        int4 q = *(const int4*)(deg + i0);
        v0 = q.x; v1 = q.y; v2 = q.z; v3 = q.w;
      } else if (i0 < n) {
        v0 = deg[i0];
        if (i0 + 1 < n) v1 = deg[i0 + 1];
        if (i0 + 2 < n) v2 = deg[i0 + 2];
      }
      int tsum = v0 + v1 + v2 + v3;
      int x = tsum;
#pragma unroll
      for (int off = 1; off < 64; off <<= 1) {
        int y = __shfl_up(x, off);
        if (lane >= off) x += y;
      }
      if (lane == 63) wsums[wid] = x;
      __syncthreads();
      if (wid == 0) {
        int ws = (lane < 16) ? wsums[lane] : 0;
#pragma unroll
        for (int off = 1; off < 16; off <<= 1) {
          int y = __shfl_up(ws, off);
          if (lane >= off) ws += y;
        }
        if (lane < 16) wsums[lane] = ws;
      }
      __syncthreads();
      int prefix = carry + ((wid > 0) ? wsums[wid - 1] : 0) + x - tsum;
      int e0 = prefix, e1 = e0 + v0, e2 = e1 + v1, e3 = e2 + v2;
      if (i0 < n)     { offs[i0] = e0;     cur[i0] = e0; }
      if (i0 + 1 < n) { offs[i0 + 1] = e1; cur[i0 + 1] = e1; }
      if (i0 + 2 < n) { offs[i0 + 2] = e2; cur[i0 + 2] = e2; }
      if (i0 + 3 < n) { offs[i0 + 3] = e3; cur[i0 + 3] = e3; }
      int btot = wsums[15];
      __syncthreads();
      carry += btot;
    }
    if (tid == 0) offs[n] = carry;
    __syncthreads();
    if (tid < NBUK) {
      int idx = tid << BSHIFT;
      bcur[tid * 16] = offs[idx < n ? idx : n];
    }
    return;
  }
  // ---- prep_xa: 16 waves/block, one node per wave ----
  const int nn = (blockIdx.x - 1) * 16 + wid;
  if (nn >= Npad) return;
  if (nn >= N) {                           // zero-pad row (wave-uniform branch)
    *(unsigned*)(ga + (size_t)nn * KTOT + 512 + 2 * lane) = 0;
    return;
  }
  float2 xv = *(const float2*)(x0 + (size_t)nn * D + 2 * lane);
  unsigned packed = (unsigned)f2bf(xv.x) | ((unsigned)f2bf(xv.y) << 16);
  *(unsigned*)(ga + (size_t)nn * KTOT + 512 + 2 * lane) = packed;
  float d[5];
#pragma unroll
  for (int b = 0; b < 4; ++b) {
    float2 w = *(const float2*)(av + b * D + 2 * lane);
    d[b] = xv.x * w.x + xv.y * w.y;
  }
  {
    float2 w = *(const float2*)(av + 512 + 2 * lane);
    d[4] = xv.x * w.x + xv.y * w.y;
  }
#pragma unroll
  for (int off = 1; off < 64; off <<= 1) {
#pragma unroll
    for (int i = 0; i < 5; ++i) d[i] += __shfl_xor(d[i], off);
  }
  if (lane == 0) {
    *(float4*)(ajb + (size_t)nn * 4) = make_float4(d[0], d[1], d[2], d[3]);
    ai[nn] = d[4];
  }
}

// Pass B: bucket edges by dst>>BSHIFT into ebuf (8B records, ~contiguous runs per bucket)
__global__ void __launch_bounds__(1024) bucket_kernel(
    const int* __restrict__ src, const int* __restrict__ dst, const int* __restrict__ et,
    int* __restrict__ bcur, unsigned long long* __restrict__ ebuf, int E) {
  __shared__ int lcnt[NBUK];
  __shared__ int lbase[NBUK];
  const int tid = threadIdx.x;
  const int e = blockIdx.x * 1024 + tid;
  if (tid < NBUK) lcnt[tid] = 0;
  __syncthreads();
  int d = 0, b = 0, rank = 0;
  unsigned pk = 0;
  bool valid = e < E;
  if (valid) {
    d = dst[e];
    pk = (unsigned)src[e] | ((unsigned)et[e] << 16);
    b = d >> BSHIFT;
    rank = atomicAdd(&lcnt[b], 1);
  }
  __syncthreads();
  if (tid < NBUK && lcnt[tid] > 0) lbase[tid] = atomicAdd(&bcur[tid * 16], lcnt[tid]);
  __syncthreads();
  if (valid) ebuf[lbase[b] + rank] = ((unsigned long long)(unsigned)d << 32) | pk;
}

// Pass C: scatter bucket-sorted records into csr (writes confined to ~130KB regions -> L2-merged)
__global__ void scatter2_kernel(const unsigned long long* __restrict__ ebuf,
                                int* __restrict__ cur, unsigned* __restrict__ csr, int E) {
  int e = blockIdx.x * 256 + threadIdx.x;
  if (e < E) {
    unsigned long long r = ebuf[e];
    int d = (int)(r >> 32);
    int pos = atomicAdd(&cur[d], 1);
    csr[pos] = (unsigned)r;
  }
}

// ---------------- softmax + x-space scatter: 4 NODES/WAVE, 16 lanes/node ----------
// No max-subtraction: |alpha| <= ||x||*||att|| < ~8 deterministically -> exp fp32-safe.
// One 16-node tile per block (3125 blocks: best measured residency/tail profile).
// LDS group stride 17 (conflict-free broadcast). 8-DEEP gather batches: 8 random rows
// in flight per wave -> 2 exposed latency round-trips per 16-edge chunk instead of 4.
__global__ void __launch_bounds__(256) node_flash(
    unsigned short* __restrict__ ga, const float* __restrict__ ai, const float* __restrict__ ajb,
    const int* __restrict__ offs, const unsigned* __restrict__ csr,
    const float* __restrict__ attr_l, int N) {
  __shared__ float s_c[NR * NB];
  __shared__ float4 s_wc[4][68];          // group g owns [g*17, g*17+16)
  __shared__ unsigned s_pk[4][68];
  const int w = threadIdx.x >> 6, lane = threadIdx.x & 63;
  const int g = lane >> 4, s = lane & 15;
  const int gb = g * 17;
  const int n = blockIdx.x * 16 + w * 4 + g;
  if (lane < NR * NB) s_c[lane] = attr_l[lane];  // all waves write identical values (benign)
  const unsigned short* gax = ga + 512u + (unsigned)s * 8u;
  int b0 = 0, b1 = 0;
  float ain = 0.f;
  if (n < N) { b0 = offs[n]; b1 = offs[n + 1]; ain = ai[n]; }
  float ssum = 0.f;
  f32x2 acc[4][4];                        // [base][dim-pair]
#pragma unroll
  for (int b = 0; b < 4; ++b)
#pragma unroll
    for (int k = 0; k < 4; ++k) acc[b][k] = (f32x2){0.f, 0.f};

  int nch = (b1 - b0 + 15) >> 4;
  nch = max(nch, __shfl_xor(nch, 16));          // wave-uniform max over 4 groups
  nch = max(nch, __shfl_xor(nch, 32));

  for (int ch = 0; ch < nch; ++ch) {
    const int cb = b0 + (ch << 4);
    const int cnt = min(16, b1 - cb);           // may be <=0 for finished groups
    float4 wc = make_float4(0.f, 0.f, 0.f, 0.f);
    unsigned pk = 0;
    if (s < cnt) {
      pk = csr[cb + s];
      unsigned sn = pk & 0xFFFFu, rt = pk >> 16;
      float4 aj = *(const float4*)(ajb + (size_t)sn * 4);
      float4 cv = *(const float4*)(&s_c[rt * 4]);
      float a = ain + cv.x * aj.x + cv.y * aj.y + cv.z * aj.z + cv.w * aj.w;
      a = fmaxf(a, SLOPE * a);                  // leaky_relu (slope<1)
      float ex = __expf(a);
      ssum += ex;                               // per-lane partial; reduced once at end
      wc = make_float4(ex * cv.x, ex * cv.y, ex * cv.z, ex * cv.w);
    }
    s_pk[w][gb + s] = pk;                       // ALL 16 slots written every chunk
    s_wc[w][gb + s] = wc;                       // pad slots: wc=0 -> contributes nothing
    int cc = max(cnt, 0);
    cc = max(cc, __shfl_xor(cc, 16));           // wave-uniform j bound
    cc = max(cc, __shfl_xor(cc, 32));
    cc = (cc + 7) & ~7;                         // round to 8: pad slots are zeroed
    const float4* wrow = &s_wc[w][gb];
    const unsigned* prow = &s_pk[w][gb];
    // wave-private LDS region: same-wave write->read ordering via lgkmcnt (compiler)
#define ACCROW(WC, QQ) { \
    f32x2 W0 = {(WC).x, (WC).x}, W1 = {(WC).y, (WC).y}; \
    f32x2 W2 = {(WC).z, (WC).z}, W3 = {(WC).w, (WC).w}; \
    f32x2 X0 = { __uint_as_float((QQ).x << 16), __uint_as_float((QQ).x & 0xFFFF0000u) }; \
    f32x2 X1 = { __uint_as_float((QQ).y << 16), __uint_as_float((QQ).y & 0xFFFF0000u) }; \
    f32x2 X2 = { __uint_as_float((QQ).z << 16), __uint_as_float((QQ).z & 0xFFFF0000u) }; \
    f32x2 X3 = { __uint_as_float((QQ).w << 16), __uint_as_float((QQ).w & 0xFFFF0000u) }; \
    acc[0][0] = __builtin_elementwise_fma(W0, X0, acc[0][0]); \
    acc[0][1] = __builtin_elementwise_fma(W0, X1, acc[0][1]); \
    acc[0][2] = __builtin_elementwise_fma(W0, X2, acc[0][2]); \
    acc[0][3] = __builtin_elementwise_fma(W0, X3, acc[0][3]); \
    acc[1][0] = __builtin_elementwise_fma(W1, X0, acc[1][0]); \
    acc[1][1] = __builtin_elementwise_fma(W1, X1, acc[1][1]); \
    acc[1][2] = __builtin_elementwise_fma(W1, X2, acc[1][2]); \
    acc[1][3] = __builtin_elementwise_fma(W1, X3, acc[1][3]); \
    acc[2][0] = __builtin_elementwise_fma(W2, X0, acc[2][0]); \
    acc[2][1] = __builtin_elementwise_fma(W2, X1, acc[2][1]); \
    acc[2][2] = __builtin_elementwise_fma(W2, X2, acc[2][2]); \
    acc[2][3] = __builtin_elementwise_fma(W2, X3, acc[2][3]); \
    acc[3][0] = __builtin_elementwise_fma(W3, X0, acc[3][0]); \
    acc[3][1] = __builtin_elementwise_fma(W3, X1, acc[3][1]); \
    acc[3][2] = __builtin_elementwise_fma(W3, X2, acc[3][2]); \
    acc[3][3] = __builtin_elementwise_fma(W3, X3, acc[3][3]); }
    for (int jb = 0; jb < cc; jb += 8) {
      // read all 8 edges' LDS metadata, issue all 8 gathers, THEN consume:
      // 8 x 1KB random-row loads in flight per wave (compiler waits per-use via vmcnt).
      unsigned p0 = prow[jb + 0], p1 = prow[jb + 1], p2 = prow[jb + 2], p3 = prow[jb + 3];
      unsigned p4 = prow[jb + 4], p5 = prow[jb + 5], p6 = prow[jb + 6], p7 = prow[jb + 7];
      const uint4 q0 = *(const uint4*)(gax + (p0 & 0xFFFFu) * (unsigned)KTOT);
      const uint4 q1 = *(const uint4*)(gax + (p1 & 0xFFFFu) * (unsigned)KTOT);
      const uint4 q2 = *(const uint4*)(gax + (p2 & 0xFFFFu) * (unsigned)KTOT);
      const uint4 q3 = *(const uint4*)(gax + (p3 & 0xFFFFu) * (unsigned)KTOT);
      const uint4 q4 = *(const uint4*)(gax + (p4 & 0xFFFFu) * (unsigned)KTOT);
      const uint4 q5 = *(const uint4*)(gax + (p5 & 0xFFFFu) * (unsigned)KTOT);
      const uint4 q6 = *(const uint4*)(gax + (p6 & 0xFFFFu) * (unsigned)KTOT);
      const uint4 q7 = *(const uint4*)(gax + (p7 & 0xFFFFu) * (unsigned)KTOT);
      float4 w0 = wrow[jb + 0], w1 = wrow[jb + 1], w2 = wrow[jb + 2], w3 = wrow[jb + 3];
      float4 w4 = wrow[jb + 4], w5 = wrow[jb + 5], w6 = wrow[jb + 6], w7 = wrow[jb + 7];
      ACCROW(w0, q0) ACCROW(w1, q1) ACCROW(w2, q2) ACCROW(w3, q3)
      ACCROW(w4, q4) ACCROW(w5, q5) ACCROW(w6, q6) ACCROW(w7, q7)
    }
#undef ACCROW
  }
  // group-wide softmax denominator (offsets <16 stay inside the 16-lane group)
#pragma unroll
  for (int off = 1; off < 16; off <<= 1) ssum += __shfl_xor(ssum, off);
  if (n < N) {
    const float inv = 1.f / (ssum + 1e-16f);
    unsigned short* gp = ga + (size_t)n * KTOT;
#pragma unroll
    for (int b = 0; b < 4; ++b) {
      uint4 r;
      r.x = (unsigned)f2bf(acc[b][0].x * inv) | ((unsigned)f2bf(acc[b][0].y * inv) << 16);
      r.y = (unsigned)f2bf(acc[b][1].x * inv) | ((unsigned)f2bf(acc[b][1].y * inv) << 16);
      r.z = (unsigned)f2bf(acc[b][2].x * inv) | ((unsigned)f2bf(acc[b][2].y * inv) << 16);
      r.w = (unsigned)f2bf(acc[b][3].x * inv) | ((unsigned)f2bf(acc[b][3].y * inv) << 16);
      *(uint4*)(gp + b * D + s * 8) = r;        // 16 lanes x 16B = contiguous 256B/base
    }
  }
}

// ---------------- MFMA GEMM: out = tanh(LN(ga[N,640]@W[640,128] + bias)) ----------------
// 512 thr = 8 waves, 128 rows/block. B staged in 10 k-chunks of 64 (18.4 KB LDS).
// Layer 0 additionally fuses a2: next-layer attention scalars ai/ajb from the val registers.
__global__ void __launch_bounds__(512) gemm2_kernel(
    unsigned short* __restrict__ ga, const unsigned short* __restrict__ BT,
    const float* __restrict__ bias_l, const float* __restrict__ lnw_l,
    const float* __restrict__ lnb_l, float* __restrict__ st,
    float* __restrict__ xfinal, const float* __restrict__ avp,
    float* __restrict__ ai, float* __restrict__ ajb, int n_nodes) {
  __shared__ unsigned short sB[128 * 72];      // [col][k] stride 72 shorts (144 B)
  const int tid = threadIdx.x;
  const int wv = tid >> 6, lane = tid & 63;
  const int l15 = lane & 15, quad = lane >> 4;
  const int rowb = blockIdx.x * 128 + wv * 16;
  const unsigned short* garow = ga + (size_t)(rowb + l15) * KTOT;
  f32x4 acc[8];
  const f32x4 zero = {0.f, 0.f, 0.f, 0.f};
#pragma unroll
  for (int ct = 0; ct < 8; ++ct) acc[ct] = zero;
#pragma unroll
  for (int ch = 0; ch < 10; ++ch) {
    const int k0 = ch * 64;
    short8 a[2];
#pragma unroll
    for (int kc = 0; kc < 2; ++kc)
      a[kc] = *(const short8*)(garow + k0 + kc * 32 + quad * 8);
    __syncthreads();                            // sB consumers of prev chunk done
#pragma unroll
    for (int p = 0; p < 2; ++p) {
      int idx = p * 512 + tid;                  // 1024 = 128 cols x 8 k8
      int col = idx >> 3, k8 = idx & 7;
      *(short8*)(sB + col * 72 + k8 * 8) =
          *(const short8*)(BT + (size_t)col * KTOT + k0 + k8 * 8);
    }
    __syncthreads();
#pragma unroll
    for (int kc = 0; kc < 2; ++kc) {
#pragma unroll
      for (int ct = 0; ct < 8; ++ct) {
        const short8* b = (const short8*)(sB + (ct * 16 + l15) * 72 + kc * 32 + quad * 8);
        acc[ct] = __builtin_amdgcn_mfma_f32_16x16x32_bf16(a[kc], *b, acc[ct], 0, 0, 0);
      }
    }
  }
  // epilogue: + bias, LayerNorm over 128 cols, tanh; write st/xfinal fp32 + next-layer xb bf16
  const int r0 = rowb + quad * 4;
  float bia[8], lw[8], lb[8];
#pragma unroll
  for (int ct = 0; ct < 8; ++ct) {
    int col = ct * 16 + l15;
    bia[ct] = bias_l[col]; lw[ct] = lnw_l[col]; lb[ct] = lnb_l[col];
  }
  float vsum[4] = {0.f, 0.f, 0.f, 0.f}, vsq[4] = {0.f, 0.f, 0.f, 0.f};
#pragma unroll
  for (int ct = 0; ct < 8; ++ct) {
#pragma unroll
    for (int r = 0; r < 4; ++r) {
      float v = acc[ct][r] + bia[ct];
      acc[ct][r] = v;
      vsum[r] += v; vsq[r] += v * v;
    }
  }
#pragma unroll
  for (int r = 0; r < 4; ++r) {
#pragma unroll
    for (int off = 1; off < 16; off <<= 1) {
      vsum[r] += __shfl_xor(vsum[r], off);
      vsq[r]  += __shfl_xor(vsq[r], off);
    }
  }
  float mu[4], rs[4];
#pragma unroll
  for (int r = 0; r < 4; ++r) {
    mu[r] = vsum[r] * (1.0f / D);
    float var = vsq[r] * (1.0f / D) - mu[r] * mu[r];
    rs[r] = rsqrtf(var + EPSV);
  }
  float part[4][5];
#pragma unroll
  for (int r = 0; r < 4; ++r)
#pragma unroll
    for (int b = 0; b < 5; ++b) part[r][b] = 0.f;
#pragma unroll
  for (int ct = 0; ct < 8; ++ct) {
    int col = ct * 16 + l15;
    float a0 = 0.f, a1 = 0.f, a2v = 0.f, a3 = 0.f, a4 = 0.f;
    if (avp) {
      a0 = avp[col]; a1 = avp[D + col]; a2v = avp[2 * D + col];
      a3 = avp[3 * D + col]; a4 = avp[4 * D + col];
    }
#pragma unroll
    for (int r = 0; r < 4; ++r) {
      int row = r0 + r;
      if (row >= n_nodes) continue;
      float nv = (acc[ct][r] - mu[r]) * rs[r] * lw[ct] + lb[ct];
      float val = tanhf(nv);
      st[(size_t)row * D + col] = val;
      if (xfinal) xfinal[(size_t)row * D + col] = val;
      ga[(size_t)row * KTOT + 512 + col] = f2bf(val);   // next-layer xb (own rows, post-read)
      if (avp) {
        part[r][0] = fmaf(val, a0, part[r][0]);
        part[r][1] = fmaf(val, a1, part[r][1]);
        part[r][2] = fmaf(val, a2v, part[r][2]);
        part[r][3] = fmaf(val, a3, part[r][3]);
        part[r][4] = fmaf(val, a4, part[r][4]);
      }
    }
  }
  if (avp) {                                    // fused a2: reduce over the 16 col-lanes
#pragma unroll
    for (int off = 1; off < 16; off <<= 1)
#pragma unroll
      for (int r = 0; r < 4; ++r)
#pragma unroll
        for (int b = 0; b < 5; ++b) part[r][b] += __shfl_xor(part[r][b], off);
    if (l15 == 0) {
#pragma unroll
      for (int r = 0; r < 4; ++r) {
        int row = r0 + r;
        if (row < n_nodes) {
          *(float4*)(ajb + (size_t)row * 4) =
              make_float4(part[r][0], part[r][1], part[r][2], part[r][3]);
          ai[row] = part[r][4];
        }
      }
    }
  }
}

// ---------------- launch ----------------
extern "C" void kernel_launch(void* const* d_in, const int* in_sizes, int n_in,
                              void* d_out, int out_size, void* d_ws, size_t ws_size,
                              hipStream_t stream) {
  const float* x0    = (const float*)d_in[0];
  const int*   ei    = (const int*)d_in[1];
  const int*   etype = (const int*)d_in[2];
  const float* basis = (const float*)d_in[3];
  const float* att_r = (const float*)d_in[4];
  const float* att   = (const float*)d_in[5];
  const float* root  = (const float*)d_in[6];
  const float* bias  = (const float*)d_in[7];
  const float* lnw   = (const float*)d_in[8];
  const float* lnb   = (const float*)d_in[9];
  float* out = (float*)d_out;
  const int N = in_sizes[0] / D;
  const int E = in_sizes[2];
  const int Npad = ((N + 127) / 128) * 128;

  char* p = (char*)d_ws;
  auto alloc = [&](size_t bytes) { void* r = (void*)p; p += (bytes + 255) & ~(size_t)255; return r; };
  unsigned short*     ga   = (unsigned short*)alloc((size_t)Npad * KTOT * 2);  // [g(512) | xb(128)]
  unsigned short*     BT0  = (unsigned short*)alloc((size_t)D * KTOT * 2);
  unsigned short*     BT1  = (unsigned short*)alloc((size_t)D * KTOT * 2);
  float*              av0  = (float*)alloc((size_t)KTOT * 4);
  float*              av1  = (float*)alloc((size_t)KTOT * 4);
  float*              ai   = (float*)alloc((size_t)N * 4);
  float*              ajb  = (float*)alloc((size_t)N * 4 * 4);
  int*                deg  = (int*)alloc((size_t)N * 4);
  int*                offs = (int*)alloc((size_t)(N + 1) * 4);
  int*                cur  = (int*)alloc((size_t)N * 4);
  int*                bcur = (int*)alloc((size_t)NBUK * 16 * 4);
  unsigned*           csr  = (unsigned*)alloc((size_t)E * 4);
  unsigned long long* ebuf = (unsigned long long*)alloc((size_t)E * 8);

  const int* srcp = ei;
  const int* dstp = ei + E;

  hipMemsetAsync(deg, 0, (size_t)N * 4, stream);
  // fused prep_w + hist (independent work, one dispatch)
  prepw_hist<<<320 + (E + 255) / 256, 256, 0, stream>>>(basis, root, att, BT0, BT1,
                                                        av0, av1, dstp, deg, E);
  // fused scan (block 0) + prep_xa (other blocks): hides the serial scan
  scan_prepxa<<<1 + Npad / 16, 1024, 0, stream>>>(deg, offs, cur, bcur, N,
                                                  x0, av0, ga, ai, ajb, N, Npad);
  bucket_kernel<<<(E + 1023) / 1024, 1024, 0, stream>>>(srcp, dstp, etype, bcur, ebuf, E);
  scatter2_kernel<<<(E + 255) / 256, 256, 0, stream>>>(ebuf, cur, csr, E);

  float* states = out + (size_t)N * D;  // [L, N, D]
  for (int l = 0; l < NLAYER; ++l) {
    const unsigned short* BT_l = l ? BT1 : BT0;
    node_flash<<<(N + 15) / 16, 256, 0, stream>>>(ga, ai, ajb, offs, csr,
                                                  att_r + (size_t)l * NR * NB, N);
    float* st = states + (size_t)l * N * D;
    gemm2_kernel<<<Npad / 128, 512, 0, stream>>>(ga, BT_l, bias + (size_t)l * D,
                                                 lnw + (size_t)l * D, lnb + (size_t)l * D,
                                                 st, (l == NLAYER - 1) ? out : nullptr,
                                                 (l == 0) ? av1 : nullptr, ai, ajb, N);
  }
}

// Round 6
// 368.050 us; speedup vs baseline: 1.1356x; 1.0238x over previous
//
#include <hip/hip_runtime.h>
#include <math.h>

#define D 128
#define NB 4      // num bases
#define NR 8      // num relations
#define NLAYER 2
#define KTOT 640  // 512 (bases) + 128 (root)
#define EPSV 1e-5f
#define SLOPE 0.2f
#define NBUK 32
#define BSHIFT 11   // bucket = dst >> 11

typedef __attribute__((ext_vector_type(8))) short short8;   // 8 bf16 = 4 VGPRs
typedef __attribute__((ext_vector_type(4))) float f32x4;
typedef __attribute__((ext_vector_type(2))) float f32x2;

__device__ __forceinline__ unsigned short f2bf(float f) {
  unsigned u = __float_as_uint(f);
  u += 0x7FFF + ((u >> 16) & 1);          // round-to-nearest-even
  return (unsigned short)(u >> 16);
}

// ---------------- fused prep_w (blocks 0..319, wave-level) + hist (all blocks) -------------
// prep_w: one k-column per wave; 64 lanes cover o in {lane, lane+64} -> pure shuffle reduce.
__global__ void __launch_bounds__(256) prepw_hist(
    const float* __restrict__ basis, const float* __restrict__ root,
    const float* __restrict__ att,
    unsigned short* __restrict__ BT0, unsigned short* __restrict__ BT1,
    float* __restrict__ av0, float* __restrict__ av1,
    const int* __restrict__ dst, int* __restrict__ deg, int E) {
  const int tid = threadIdx.x, lane = tid & 63, wid = tid >> 6;
  if (blockIdx.x < (2 * KTOT) / 4) {            // 320 blocks x 4 waves = 1280 k-columns
    const int kk = blockIdx.x * 4 + wid;
    const int l = kk >= KTOT ? 1 : 0;
    const int k = kk - l * KTOT;
    const float* basis_l = basis + (size_t)l * NB * D * D;
    const float* root_l  = root + (size_t)l * D * D;
    const float* att_l   = att + (size_t)l * 2 * D;
    unsigned short* BT = l ? BT1 : BT0;
    float* av = l ? av1 : av0;
    const int o = lane;
    float v1, v2, w1, w2;
    if (k < 512) {
      const float* bp = basis_l + (size_t)(k >> 7) * (D * D) + (size_t)(k & 127) * D;
      v1 = bp[o]; v2 = bp[o + 64];
      w1 = att_l[D + o]; w2 = att_l[D + o + 64];
    } else {
      const float* rp = root_l + (size_t)(k - 512) * D;
      v1 = rp[o]; v2 = rp[o + 64];
      w1 = att_l[o]; w2 = att_l[o + 64];
    }
    BT[(size_t)o * KTOT + k] = f2bf(v1);
    BT[(size_t)(o + 64) * KTOT + k] = f2bf(v2);
    float sv = v1 * w1 + v2 * w2;
#pragma unroll
    for (int off = 32; off > 0; off >>= 1) sv += __shfl_xor(sv, off);
    if (lane == 0) av[k] = sv;
  }
  // hist: grid-stride over edges
  const int gtid = blockIdx.x * 256 + tid;
  const int nthr = gridDim.x * 256;
  for (int e = gtid; e < E; e += nthr) atomicAdd(&deg[dst[e]], 1);
}

// ---------------- fused: block 0 = serial scan of deg; blocks >=1 = prep_xa ----------------
// Overlaps the single-block scan (GPU otherwise idle) with the N-node x prep.
__global__ void __launch_bounds__(1024) scan_prepxa(
    const int* __restrict__ deg, int* __restrict__ offs, int* __restrict__ cur,
    int* __restrict__ bcur, int n,
    const float* __restrict__ x0, const float* __restrict__ av,
    unsigned short* __restrict__ ga, float* __restrict__ ai, float* __restrict__ ajb,
    int N, int Npad) {
  __shared__ int wsums[16];
  const int tid = threadIdx.x, lane = tid & 63, wid = tid >> 6;
  if (blockIdx.x == 0) {                        // ---- serial chunked scan ----
    int carry = 0;
    for (int base = 0; base < n; base += 4096) {
      int i0 = base + tid * 4;
      int v0 = 0, v1 = 0, v2 = 0, v3 = 0;
      if (i0 + 3 < n) {
        int4 q = *(const int4*)(deg + i0);
        v0 = q.x; v1 = q.y; v2 = q.z; v3 = q.w;
      } else if (i0 < n) {
        v0 = deg[i0];
        if (i0 + 1 < n) v1 = deg[i0 + 1];
        if (i0 + 2 < n) v2 = deg[i0 + 2];
      }
      int tsum = v0 + v1 + v2 + v3;
      int x = tsum;
#pragma unroll
      for (int off = 1; off < 64; off <<= 1) {
        int y = __shfl_up(x, off);
        if (lane >= off) x += y;
      }
      if (lane == 63) wsums[wid] = x;
      __syncthreads();
      if (wid == 0) {
        int ws = (lane < 16) ? wsums[lane] : 0;
#pragma unroll
        for (int off = 1; off < 16; off <<= 1) {
          int y = __shfl_up(ws, off);
          if (lane >= off) ws += y;
        }
        if (lane < 16) wsums[lane] = ws;
      }
      __syncthreads();
      int prefix = carry + ((wid > 0) ? wsums[wid - 1] : 0) + x - tsum;
      int e0 = prefix, e1 = e0 + v0, e2 = e1 + v1, e3 = e2 + v2;
      if (i0 < n)     { offs[i0] = e0;     cur[i0] = e0; }
      if (i0 + 1 < n) { offs[i0 + 1] = e1; cur[i0 + 1] = e1; }
      if (i0 + 2 < n) { offs[i0 + 2] = e2; cur[i0 + 2] = e2; }
      if (i0 + 3 < n) { offs[i0 + 3] = e3; cur[i0 + 3] = e3; }
      int btot = wsums[15];
      __syncthreads();
      carry += btot;
    }
    if (tid == 0) offs[n] = carry;
    __syncthreads();
    if (tid < NBUK) {
      int idx = tid << BSHIFT;
      bcur[tid * 16] = offs[idx < n ? idx : n];
    }
    return;
  }
  // ---- prep_xa: 16 waves/block, one node per wave ----
  const int nn = (blockIdx.x - 1) * 16 + wid;
  if (nn >= Npad) return;
  if (nn >= N) {                           // zero-pad row (wave-uniform branch)
    *(unsigned*)(ga + (size_t)nn * KTOT + 512 + 2 * lane) = 0;
    return;
  }
  float2 xv = *(const float2*)(x0 + (size_t)nn * D + 2 * lane);
  unsigned packed = (unsigned)f2bf(xv.x) | ((unsigned)f2bf(xv.y) << 16);
  *(unsigned*)(ga + (size_t)nn * KTOT + 512 + 2 * lane) = packed;
  float d[5];
#pragma unroll
  for (int b = 0; b < 4; ++b) {
    float2 w = *(const float2*)(av + b * D + 2 * lane);
    d[b] = xv.x * w.x + xv.y * w.y;
  }
  {
    float2 w = *(const float2*)(av + 512 + 2 * lane);
    d[4] = xv.x * w.x + xv.y * w.y;
  }
#pragma unroll
  for (int off = 1; off < 64; off <<= 1) {
#pragma unroll
    for (int i = 0; i < 5; ++i) d[i] += __shfl_xor(d[i], off);
  }
  if (lane == 0) {
    *(float4*)(ajb + (size_t)nn * 4) = make_float4(d[0], d[1], d[2], d[3]);
    ai[nn] = d[4];
  }
}

// Pass B: bucket edges by dst>>BSHIFT into ebuf (8B records, ~contiguous runs per bucket)
__global__ void __launch_bounds__(1024) bucket_kernel(
    const int* __restrict__ src, const int* __restrict__ dst, const int* __restrict__ et,
    int* __restrict__ bcur, unsigned long long* __restrict__ ebuf, int E) {
  __shared__ int lcnt[NBUK];
  __shared__ int lbase[NBUK];
  const int tid = threadIdx.x;
  const int e = blockIdx.x * 1024 + tid;
  if (tid < NBUK) lcnt[tid] = 0;
  __syncthreads();
  int d = 0, b = 0, rank = 0;
  unsigned pk = 0;
  bool valid = e < E;
  if (valid) {
    d = dst[e];
    pk = (unsigned)src[e] | ((unsigned)et[e] << 16);
    b = d >> BSHIFT;
    rank = atomicAdd(&lcnt[b], 1);
  }
  __syncthreads();
  if (tid < NBUK && lcnt[tid] > 0) lbase[tid] = atomicAdd(&bcur[tid * 16], lcnt[tid]);
  __syncthreads();
  if (valid) ebuf[lbase[b] + rank] = ((unsigned long long)(unsigned)d << 32) | pk;
}

// Pass C: scatter bucket-sorted records into csr (writes confined to ~130KB regions -> L2-merged)
__global__ void scatter2_kernel(const unsigned long long* __restrict__ ebuf,
                                int* __restrict__ cur, unsigned* __restrict__ csr, int E) {
  int e = blockIdx.x * 256 + threadIdx.x;
  if (e < E) {
    unsigned long long r = ebuf[e];
    int d = (int)(r >> 32);
    int pos = atomicAdd(&cur[d], 1);
    csr[pos] = (unsigned)r;
  }
}

// ---------------- softmax + x-space scatter: ONE WAVE PER BLOCK, 4 nodes, 16 lanes/node ----
// No max-subtraction: |alpha| <= ||x||*||att|| < ~8 deterministically -> exp fp32-safe.
// 64-thr blocks (12500): block retire = max over 4 node degrees (vs 16) -> lighter tail.
// 8-deep gather batches with sched_barrier(0) pinning all 8 loads BEFORE the FMAs:
// forces 8 x 256B random-row loads in flight per wave (compiler cannot sink them).
__global__ void __launch_bounds__(64) node_flash(
    unsigned short* __restrict__ ga, const float* __restrict__ ai, const float* __restrict__ ajb,
    const int* __restrict__ offs, const unsigned* __restrict__ csr,
    const float* __restrict__ attr_l, int N) {
  __shared__ float s_c[NR * NB];
  __shared__ float4 s_wc[68];             // group g owns [g*17, g*17+16)
  __shared__ unsigned s_pk[68];
  const int lane = threadIdx.x & 63;
  const int g = lane >> 4, s = lane & 15;
  const int gb = g * 17;
  const int n = blockIdx.x * 4 + g;
  if (lane < NR * NB) s_c[lane] = attr_l[lane];
  const unsigned short* gax = ga + 512u + (unsigned)s * 8u;
  int b0 = 0, b1 = 0;
  float ain = 0.f;
  if (n < N) { b0 = offs[n]; b1 = offs[n + 1]; ain = ai[n]; }
  float ssum = 0.f;
  f32x2 acc[4][4];                        // [base][dim-pair]
#pragma unroll
  for (int b = 0; b < 4; ++b)
#pragma unroll
    for (int k = 0; k < 4; ++k) acc[b][k] = (f32x2){0.f, 0.f};

  int nch = (b1 - b0 + 15) >> 4;
  nch = max(nch, __shfl_xor(nch, 16));          // wave-uniform max over 4 groups
  nch = max(nch, __shfl_xor(nch, 32));

  for (int ch = 0; ch < nch; ++ch) {
    const int cb = b0 + (ch << 4);
    const int cnt = min(16, b1 - cb);           // may be <=0 for finished groups
    float4 wc = make_float4(0.f, 0.f, 0.f, 0.f);
    unsigned pk = 0;
    if (s < cnt) {
      pk = csr[cb + s];
      unsigned sn = pk & 0xFFFFu, rt = pk >> 16;
      float4 aj = *(const float4*)(ajb + (size_t)sn * 4);
      float4 cv = *(const float4*)(&s_c[rt * 4]);
      float a = ain + cv.x * aj.x + cv.y * aj.y + cv.z * aj.z + cv.w * aj.w;
      a = fmaxf(a, SLOPE * a);                  // leaky_relu (slope<1)
      float ex = __expf(a);
      ssum += ex;                               // per-lane partial; reduced once at end
      wc = make_float4(ex * cv.x, ex * cv.y, ex * cv.z, ex * cv.w);
    }
    s_pk[gb + s] = pk;                          // ALL 16 slots written every chunk
    s_wc[gb + s] = wc;                          // pad slots: wc=0 -> contributes nothing
    int cc = max(cnt, 0);
    cc = max(cc, __shfl_xor(cc, 16));           // wave-uniform j bound
    cc = max(cc, __shfl_xor(cc, 32));
    cc = (cc + 7) & ~7;                         // round to 8: pad slots are zeroed
    const float4* wrow = &s_wc[gb];
    const unsigned* prow = &s_pk[gb];
    // wave-private LDS: same-wave write->read ordering via lgkmcnt (compiler)
#define ACCROW(WC, QQ) { \
    f32x2 W0 = {(WC).x, (WC).x}, W1 = {(WC).y, (WC).y}; \
    f32x2 W2 = {(WC).z, (WC).z}, W3 = {(WC).w, (WC).w}; \
    f32x2 X0 = { __uint_as_float((QQ).x << 16), __uint_as_float((QQ).x & 0xFFFF0000u) }; \
    f32x2 X1 = { __uint_as_float((QQ).y << 16), __uint_as_float((QQ).y & 0xFFFF0000u) }; \
    f32x2 X2 = { __uint_as_float((QQ).z << 16), __uint_as_float((QQ).z & 0xFFFF0000u) }; \
    f32x2 X3 = { __uint_as_float((QQ).w << 16), __uint_as_float((QQ).w & 0xFFFF0000u) }; \
    acc[0][0] = __builtin_elementwise_fma(W0, X0, acc[0][0]); \
    acc[0][1] = __builtin_elementwise_fma(W0, X1, acc[0][1]); \
    acc[0][2] = __builtin_elementwise_fma(W0, X2, acc[0][2]); \
    acc[0][3] = __builtin_elementwise_fma(W0, X3, acc[0][3]); \
    acc[1][0] = __builtin_elementwise_fma(W1, X0, acc[1][0]); \
    acc[1][1] = __builtin_elementwise_fma(W1, X1, acc[1][1]); \
    acc[1][2] = __builtin_elementwise_fma(W1, X2, acc[1][2]); \
    acc[1][3] = __builtin_elementwise_fma(W1, X3, acc[1][3]); \
    acc[2][0] = __builtin_elementwise_fma(W2, X0, acc[2][0]); \
    acc[2][1] = __builtin_elementwise_fma(W2, X1, acc[2][1]); \
    acc[2][2] = __builtin_elementwise_fma(W2, X2, acc[2][2]); \
    acc[2][3] = __builtin_elementwise_fma(W2, X3, acc[2][3]); \
    acc[3][0] = __builtin_elementwise_fma(W3, X0, acc[3][0]); \
    acc[3][1] = __builtin_elementwise_fma(W3, X1, acc[3][1]); \
    acc[3][2] = __builtin_elementwise_fma(W3, X2, acc[3][2]); \
    acc[3][3] = __builtin_elementwise_fma(W3, X3, acc[3][3]); }
    for (int jb = 0; jb < cc; jb += 8) {
      // issue ALL 8 row gathers, then fence the scheduler: loads may not sink
      // below this point -> genuinely 8 x 256B loads in flight per wave.
      unsigned p0 = prow[jb + 0], p1 = prow[jb + 1], p2 = prow[jb + 2], p3 = prow[jb + 3];
      unsigned p4 = prow[jb + 4], p5 = prow[jb + 5], p6 = prow[jb + 6], p7 = prow[jb + 7];
      const uint4 q0 = *(const uint4*)(gax + (p0 & 0xFFFFu) * (unsigned)KTOT);
      const uint4 q1 = *(const uint4*)(gax + (p1 & 0xFFFFu) * (unsigned)KTOT);
      const uint4 q2 = *(const uint4*)(gax + (p2 & 0xFFFFu) * (unsigned)KTOT);
      const uint4 q3 = *(const uint4*)(gax + (p3 & 0xFFFFu) * (unsigned)KTOT);
      const uint4 q4 = *(const uint4*)(gax + (p4 & 0xFFFFu) * (unsigned)KTOT);
      const uint4 q5 = *(const uint4*)(gax + (p5 & 0xFFFFu) * (unsigned)KTOT);
      const uint4 q6 = *(const uint4*)(gax + (p6 & 0xFFFFu) * (unsigned)KTOT);
      const uint4 q7 = *(const uint4*)(gax + (p7 & 0xFFFFu) * (unsigned)KTOT);
      float4 w0 = wrow[jb + 0], w1 = wrow[jb + 1], w2 = wrow[jb + 2], w3 = wrow[jb + 3];
      float4 w4 = wrow[jb + 4], w5 = wrow[jb + 5], w6 = wrow[jb + 6], w7 = wrow[jb + 7];
      __builtin_amdgcn_sched_barrier(0);
      ACCROW(w0, q0) ACCROW(w1, q1) ACCROW(w2, q2) ACCROW(w3, q3)
      ACCROW(w4, q4) ACCROW(w5, q5) ACCROW(w6, q6) ACCROW(w7, q7)
    }
#undef ACCROW
  }
  // group-wide softmax denominator (offsets <16 stay inside the 16-lane group)
#pragma unroll
  for (int off = 1; off < 16; off <<= 1) ssum += __shfl_xor(ssum, off);
  if (n < N) {
    const float inv = 1.f / (ssum + 1e-16f);
    unsigned short* gp = ga + (size_t)n * KTOT;
#pragma unroll
    for (int b = 0; b < 4; ++b) {
      uint4 r;
      r.x = (unsigned)f2bf(acc[b][0].x * inv) | ((unsigned)f2bf(acc[b][0].y * inv) << 16);
      r.y = (unsigned)f2bf(acc[b][1].x * inv) | ((unsigned)f2bf(acc[b][1].y * inv) << 16);
      r.z = (unsigned)f2bf(acc[b][2].x * inv) | ((unsigned)f2bf(acc[b][2].y * inv) << 16);
      r.w = (unsigned)f2bf(acc[b][3].x * inv) | ((unsigned)f2bf(acc[b][3].y * inv) << 16);
      *(uint4*)(gp + b * D + s * 8) = r;        // 16 lanes x 16B = contiguous 256B/base
    }
  }
}

// ---------------- MFMA GEMM: out = tanh(LN(ga[N,640]@W[640,128] + bias)) ----------------
// 512 thr = 8 waves, 128 rows/block. B staged in 10 k-chunks of 64 (18.4 KB LDS).
// Layer 0 additionally fuses a2: next-layer attention scalars ai/ajb from the val registers.
__global__ void __launch_bounds__(512) gemm2_kernel(
    unsigned short* __restrict__ ga, const unsigned short* __restrict__ BT,
    const float* __restrict__ bias_l, const float* __restrict__ lnw_l,
    const float* __restrict__ lnb_l, float* __restrict__ st,
    float* __restrict__ xfinal, const float* __restrict__ avp,
    float* __restrict__ ai, float* __restrict__ ajb, int n_nodes) {
  __shared__ unsigned short sB[128 * 72];      // [col][k] stride 72 shorts (144 B)
  const int tid = threadIdx.x;
  const int wv = tid >> 6, lane = tid & 63;
  const int l15 = lane & 15, quad = lane >> 4;
  const int rowb = blockIdx.x * 128 + wv * 16;
  const unsigned short* garow = ga + (size_t)(rowb + l15) * KTOT;
  f32x4 acc[8];
  const f32x4 zero = {0.f, 0.f, 0.f, 0.f};
#pragma unroll
  for (int ct = 0; ct < 8; ++ct) acc[ct] = zero;
#pragma unroll
  for (int ch = 0; ch < 10; ++ch) {
    const int k0 = ch * 64;
    short8 a[2];
#pragma unroll
    for (int kc = 0; kc < 2; ++kc)
      a[kc] = *(const short8*)(garow + k0 + kc * 32 + quad * 8);
    __syncthreads();                            // sB consumers of prev chunk done
#pragma unroll
    for (int p = 0; p < 2; ++p) {
      int idx = p * 512 + tid;                  // 1024 = 128 cols x 8 k8
      int col = idx >> 3, k8 = idx & 7;
      *(short8*)(sB + col * 72 + k8 * 8) =
          *(const short8*)(BT + (size_t)col * KTOT + k0 + k8 * 8);
    }
    __syncthreads();
#pragma unroll
    for (int kc = 0; kc < 2; ++kc) {
#pragma unroll
      for (int ct = 0; ct < 8; ++ct) {
        const short8* b = (const short8*)(sB + (ct * 16 + l15) * 72 + kc * 32 + quad * 8);
        acc[ct] = __builtin_amdgcn_mfma_f32_16x16x32_bf16(a[kc], *b, acc[ct], 0, 0, 0);
      }
    }
  }
  // epilogue: + bias, LayerNorm over 128 cols, tanh; write st/xfinal fp32 + next-layer xb bf16
  const int r0 = rowb + quad * 4;
  float bia[8], lw[8], lb[8];
#pragma unroll
  for (int ct = 0; ct < 8; ++ct) {
    int col = ct * 16 + l15;
    bia[ct] = bias_l[col]; lw[ct] = lnw_l[col]; lb[ct] = lnb_l[col];
  }
  float vsum[4] = {0.f, 0.f, 0.f, 0.f}, vsq[4] = {0.f, 0.f, 0.f, 0.f};
#pragma unroll
  for (int ct = 0; ct < 8; ++ct) {
#pragma unroll
    for (int r = 0; r < 4; ++r) {
      float v = acc[ct][r] + bia[ct];
      acc[ct][r] = v;
      vsum[r] += v; vsq[r] += v * v;
    }
  }
#pragma unroll
  for (int r = 0; r < 4; ++r) {
#pragma unroll
    for (int off = 1; off < 16; off <<= 1) {
      vsum[r] += __shfl_xor(vsum[r], off);
      vsq[r]  += __shfl_xor(vsq[r], off);
    }
  }
  float mu[4], rs[4];
#pragma unroll
  for (int r = 0; r < 4; ++r) {
    mu[r] = vsum[r] * (1.0f / D);
    float var = vsq[r] * (1.0f / D) - mu[r] * mu[r];
    rs[r] = rsqrtf(var + EPSV);
  }
  float part[4][5];
#pragma unroll
  for (int r = 0; r < 4; ++r)
#pragma unroll
    for (int b = 0; b < 5; ++b) part[r][b] = 0.f;
#pragma unroll
  for (int ct = 0; ct < 8; ++ct) {
    int col = ct * 16 + l15;
    float a0 = 0.f, a1 = 0.f, a2v = 0.f, a3 = 0.f, a4 = 0.f;
    if (avp) {
      a0 = avp[col]; a1 = avp[D + col]; a2v = avp[2 * D + col];
      a3 = avp[3 * D + col]; a4 = avp[4 * D + col];
    }
#pragma unroll
    for (int r = 0; r < 4; ++r) {
      int row = r0 + r;
      if (row >= n_nodes) continue;
      float nv = (acc[ct][r] - mu[r]) * rs[r] * lw[ct] + lb[ct];
      float val = tanhf(nv);
      st[(size_t)row * D + col] = val;
      if (xfinal) xfinal[(size_t)row * D + col] = val;
      ga[(size_t)row * KTOT + 512 + col] = f2bf(val);   // next-layer xb (own rows, post-read)
      if (avp) {
        part[r][0] = fmaf(val, a0, part[r][0]);
        part[r][1] = fmaf(val, a1, part[r][1]);
        part[r][2] = fmaf(val, a2v, part[r][2]);
        part[r][3] = fmaf(val, a3, part[r][3]);
        part[r][4] = fmaf(val, a4, part[r][4]);
      }
    }
  }
  if (avp) {                                    // fused a2: reduce over the 16 col-lanes
#pragma unroll
    for (int off = 1; off < 16; off <<= 1)
#pragma unroll
      for (int r = 0; r < 4; ++r)
#pragma unroll
        for (int b = 0; b < 5; ++b) part[r][b] += __shfl_xor(part[r][b], off);
    if (l15 == 0) {
#pragma unroll
      for (int r = 0; r < 4; ++r) {
        int row = r0 + r;
        if (row < n_nodes) {
          *(float4*)(ajb + (size_t)row * 4) =
              make_float4(part[r][0], part[r][1], part[r][2], part[r][3]);
          ai[row] = part[r][4];
        }
      }
    }
  }
}

// ---------------- launch ----------------
extern "C" void kernel_launch(void* const* d_in, const int* in_sizes, int n_in,
                              void* d_out, int out_size, void* d_ws, size_t ws_size,
                              hipStream_t stream) {
  const float* x0    = (const float*)d_in[0];
  const int*   ei    = (const int*)d_in[1];
  const int*   etype = (const int*)d_in[2];
  const float* basis = (const float*)d_in[3];
  const float* att_r = (const float*)d_in[4];
  const float* att   = (const float*)d_in[5];
  const float* root  = (const float*)d_in[6];
  const float* bias  = (const float*)d_in[7];
  const float* lnw   = (const float*)d_in[8];
  const float* lnb   = (const float*)d_in[9];
  float* out = (float*)d_out;
  const int N = in_sizes[0] / D;
  const int E = in_sizes[2];
  const int Npad = ((N + 127) / 128) * 128;

  char* p = (char*)d_ws;
  auto alloc = [&](size_t bytes) { void* r = (void*)p; p += (bytes + 255) & ~(size_t)255; return r; };
  unsigned short*     ga   = (unsigned short*)alloc((size_t)Npad * KTOT * 2);  // [g(512) | xb(128)]
  unsigned short*     BT0  = (unsigned short*)alloc((size_t)D * KTOT * 2);
  unsigned short*     BT1  = (unsigned short*)alloc((size_t)D * KTOT * 2);
  float*              av0  = (float*)alloc((size_t)KTOT * 4);
  float*              av1  = (float*)alloc((size_t)KTOT * 4);
  float*              ai   = (float*)alloc((size_t)N * 4);
  float*              ajb  = (float*)alloc((size_t)N * 4 * 4);
  int*                deg  = (int*)alloc((size_t)N * 4);
  int*                offs = (int*)alloc((size_t)(N + 1) * 4);
  int*                cur  = (int*)alloc((size_t)N * 4);
  int*                bcur = (int*)alloc((size_t)NBUK * 16 * 4);
  unsigned*           csr  = (unsigned*)alloc((size_t)E * 4);
  unsigned long long* ebuf = (unsigned long long*)alloc((size_t)E * 8);

  const int* srcp = ei;
  const int* dstp = ei + E;

  hipMemsetAsync(deg, 0, (size_t)N * 4, stream);
  // fused prep_w + hist (independent work, one dispatch)
  prepw_hist<<<320 + (E + 255) / 256, 256, 0, stream>>>(basis, root, att, BT0, BT1,
                                                        av0, av1, dstp, deg, E);
  // fused scan (block 0) + prep_xa (other blocks): hides the serial scan
  scan_prepxa<<<1 + Npad / 16, 1024, 0, stream>>>(deg, offs, cur, bcur, N,
                                                  x0, av0, ga, ai, ajb, N, Npad);
  bucket_kernel<<<(E + 1023) / 1024, 1024, 0, stream>>>(srcp, dstp, etype, bcur, ebuf, E);
  scatter2_kernel<<<(E + 255) / 256, 256, 0, stream>>>(ebuf, cur, csr, E);

  float* states = out + (size_t)N * D;  // [L, N, D]
  for (int l = 0; l < NLAYER; ++l) {
    const unsigned short* BT_l = l ? BT1 : BT0;
    node_flash<<<(N + 3) / 4, 64, 0, stream>>>(ga, ai, ajb, offs, csr,
                                               att_r + (size_t)l * NR * NB, N);
    float* st = states + (size_t)l * N * D;
    gemm2_kernel<<<Npad / 128, 512, 0, stream>>>(ga, BT_l, bias + (size_t)l * D,
                                                 lnw + (size_t)l * D, lnb + (size_t)l * D,
                                                 st, (l == NLAYER - 1) ? out : nullptr,
                                                 (l == 0) ? av1 : nullptr, ai, ajb, N);
  }
}